// Round 1
// baseline (705.320 us; speedup 1.0000x reference)
//
#include <hip/hip_runtime.h>
#include <hip/hip_bf16.h>

// GCN link predictor, Round 10: replace the 4-kernel bucketed counting sort
// (bin_count / bin_scan / partition / bucket_sort, 115MB traffic, payload
// round-trip, two latency-bound kernel shapes) with a direct 2-pass COO->CSR
// scatter using global per-row cursors. Legal because within-row order of
// csr entries is irrelevant (SPMM sums them; cursor order was already
// nondeterministic via atomics).
//   pass 1: rowcnt[dst[e]]++  (3.2M device atomics into 400KB, L2-resident)
//   scan:   2 tiny hierarchical-scan kernels -> rs (inclusive ends) + cur
//   pass 2: csr[atomicAdd(&cur[dst],1)] = src<<15 | q15(val)
// All replacement kernels are max-occupancy grid-stride, no LDS staging.
// GEMM1 (MFMA), SPMM (16/8-lane teams), GEMM2, decode unchanged from R9.

#define D_IN  256
#define D_HID 64
#define D_EMB 32
#define SCAN_ELEMS 1024   // rows per scan block (256 thr x 4)

typedef unsigned short u16;
typedef unsigned int u32;
typedef __attribute__((ext_vector_type(8))) short short8;   // 8 bf16
typedef __attribute__((ext_vector_type(4))) float f32x4;

__device__ __forceinline__ float bf2f(u32 u) {
  return __uint_as_float((u & 0xFFFFu) << 16);
}
__device__ __forceinline__ float bf2f_hi(u32 u) {
  return __uint_as_float(u & 0xFFFF0000u);
}
__device__ __forceinline__ u16 f2bf(float f) {
  u32 x = __float_as_uint(f);
  x += 0x7FFFu + ((x >> 16) & 1u);  // RNE
  return (u16)(x >> 16);
}
__device__ __forceinline__ void unpack8(uint4 u, float* f) {
  f[0] = bf2f(u.x); f[1] = bf2f(u.x >> 16);
  f[2] = bf2f(u.y); f[3] = bf2f(u.y >> 16);
  f[4] = bf2f(u.z); f[5] = bf2f(u.z >> 16);
  f[6] = bf2f(u.w); f[7] = bf2f(u.w >> 16);
}

// ---------------------------------------------------------------------------
// One-time W1 swizzle: fp32 [256,64] -> bf16 B-fragments.
__global__ __launch_bounds__(256) void w1_swizzle_kernel(
    const float* __restrict__ W1, uint4* __restrict__ gswz) {
  const int s = blockIdx.x * 256 + threadIdx.x;  // 2048 slots
  const int lane = s & 63;
  const int kstep = (s >> 6) & 7;
  const int nt = s >> 9;
  const int col = nt * 16 + (lane & 15);
  const int kbase = kstep * 32 + (lane >> 4) * 8;
  u32 p[4];
  for (int jp = 0; jp < 4; ++jp) {
    u32 lo = f2bf(W1[(kbase + 2 * jp) * D_HID + col]);
    u32 hi = f2bf(W1[(kbase + 2 * jp + 1) * D_HID + col]);
    p[jp] = lo | (hi << 16);
  }
  gswz[s] = make_uint4(p[0], p[1], p[2], p[3]);
}

// ---------------------------------------------------------------------------
// Pass 1: per-row histogram. Uniform-random rows over 100K bins -> negligible
// same-address contention; bins array (400KB) is L2-resident.
__global__ __launch_bounds__(256) void hist_kernel(
    const int* __restrict__ dst, int* __restrict__ rowcnt, int nnz) {
  const int stride = gridDim.x * 256;
  const int n4 = nnz >> 2;
  const int4* d4 = (const int4*)dst;
  for (int i = blockIdx.x * 256 + threadIdx.x; i < n4; i += stride) {
    int4 d = d4[i];
    atomicAdd(&rowcnt[d.x], 1);
    atomicAdd(&rowcnt[d.y], 1);
    atomicAdd(&rowcnt[d.z], 1);
    atomicAdd(&rowcnt[d.w], 1);
  }
  for (int e = (n4 << 2) + blockIdx.x * 256 + threadIdx.x; e < nnz; e += stride)
    atomicAdd(&rowcnt[dst[e]], 1);
}

// Scan stage A: per-block (1024-row) sums.
__global__ __launch_bounds__(256) void scan_blocksum_kernel(
    const int* __restrict__ rowcnt, int* __restrict__ bsum, int M) {
  __shared__ int sm[256];
  const int t = threadIdx.x;
  const int base = blockIdx.x * SCAN_ELEMS + t * 4;
  int s = 0;
  if (base + 3 < M) {
    int4 v = *(const int4*)&rowcnt[base];
    s = v.x + v.y + v.z + v.w;
  } else {
    for (int i = 0; i < 4; ++i)
      if (base + i < M) s += rowcnt[base + i];
  }
  sm[t] = s;
  __syncthreads();
  for (int off = 128; off > 0; off >>= 1) {
    if (t < off) sm[t] += sm[t + off];
    __syncthreads();
  }
  if (t == 0) bsum[blockIdx.x] = sm[0];
}

// Scan stage B: each block derives its global base from bsum (NB <= 256),
// does a block-local scan of 1024 rowcnts, writes cur (row starts) and
// rs (inclusive row ends, same semantics the SPMM consumes).
__global__ __launch_bounds__(256) void scan_write_kernel(
    const int* __restrict__ rowcnt, const int* __restrict__ bsum,
    int* __restrict__ rs, int* __restrict__ cur, int M, int NB) {
  __shared__ int sm[256];
  __shared__ int sbase;
  const int t = threadIdx.x;
  const int b = blockIdx.x;

  // exclusive sum of bsum[0..b)
  int v = (t < b && t < NB) ? bsum[t] : 0;
  sm[t] = v;
  __syncthreads();
  for (int off = 128; off > 0; off >>= 1) {
    if (t < off) sm[t] += sm[t + off];
    __syncthreads();
  }
  if (t == 0) sbase = sm[0];
  __syncthreads();

  const int base = b * SCAN_ELEMS + t * 4;
  int c[4];
  int s = 0;
  for (int i = 0; i < 4; ++i) {
    int idx = base + i;
    c[i] = (idx < M) ? rowcnt[idx] : 0;
    s += c[i];
  }
  sm[t] = s;
  __syncthreads();
  for (int off = 1; off < 256; off <<= 1) {
    int tmp = (t >= off) ? sm[t - off] : 0;
    __syncthreads();
    sm[t] += tmp;
    __syncthreads();
  }
  int start = sbase + sm[t] - s;  // exclusive prefix for this thread's 4 rows
  for (int i = 0; i < 4; ++i) {
    int idx = base + i;
    if (idx < M) {
      cur[idx] = start;
      start += c[i];
      rs[idx] = start;  // inclusive end
    }
  }
}

// Pass 2: scatter into final CSR slots. Random 4B stores to distinct bytes
// merge via dirty-byte tracking in L2 (write-only false sharing is safe).
__global__ __launch_bounds__(256) void scatter_kernel(
    const int* __restrict__ src, const int* __restrict__ dst,
    const float* __restrict__ val, int* __restrict__ cur,
    u32* __restrict__ csr, int nnz) {
  const int stride = gridDim.x * 256;
  const int n4 = nnz >> 2;
  const int4* s4 = (const int4*)src;
  const int4* d4 = (const int4*)dst;
  const float4* v4 = (const float4*)val;
  for (int i = blockIdx.x * 256 + threadIdx.x; i < n4; i += stride) {
    int4 s = s4[i];
    int4 d = d4[i];
    float4 v = v4[i];
    int q0 = min((int)(v.x * 32768.f + 0.5f), 32767);
    int q1 = min((int)(v.y * 32768.f + 0.5f), 32767);
    int q2 = min((int)(v.z * 32768.f + 0.5f), 32767);
    int q3 = min((int)(v.w * 32768.f + 0.5f), 32767);
    int p0 = atomicAdd(&cur[d.x], 1);
    int p1 = atomicAdd(&cur[d.y], 1);
    int p2 = atomicAdd(&cur[d.z], 1);
    int p3 = atomicAdd(&cur[d.w], 1);
    csr[p0] = ((u32)s.x << 15) | (u32)q0;
    csr[p1] = ((u32)s.y << 15) | (u32)q1;
    csr[p2] = ((u32)s.z << 15) | (u32)q2;
    csr[p3] = ((u32)s.w << 15) | (u32)q3;
  }
  for (int e = (n4 << 2) + blockIdx.x * 256 + threadIdx.x; e < nnz; e += stride) {
    int q = min((int)(val[e] * 32768.f + 0.5f), 32767);
    int p = atomicAdd(&cur[dst[e]], 1);
    csr[p] = ((u32)src[e] << 15) | (u32)q;
  }
}

// ---------------------------------------------------------------------------
// GEMM1 via MFMA: h1[M,64](bf16) = x[M,256](f32 -> bf16) @ W1.
__global__ __launch_bounds__(256) void gemm1_mfma_kernel(
    const float* __restrict__ x, const uint4* __restrict__ gswz,
    u16* __restrict__ h1, int M) {
  const int tid = threadIdx.x;
  const int wv = tid >> 6;
  const int lane = tid & 63;
  const int quad = lane >> 4;
  const int m = lane & 15;

  const int rowbase = blockIdx.x * 64 + wv * 16;
  int arow = rowbase + m;
  if (arow >= M) arow = M - 1;

  f32x4 acc[4];
  for (int nt = 0; nt < 4; ++nt) acc[nt] = (f32x4){0.f, 0.f, 0.f, 0.f};

  const float* xrow = &x[(long long)arow * D_IN];

#pragma unroll
  for (int kstep = 0; kstep < 8; ++kstep) {
    const int kbase = kstep * 32 + quad * 8;
    float4 a0 = *(const float4*)&xrow[kbase];
    float4 a1 = *(const float4*)&xrow[kbase + 4];
    short8 af;
    af[0] = (short)f2bf(a0.x); af[1] = (short)f2bf(a0.y);
    af[2] = (short)f2bf(a0.z); af[3] = (short)f2bf(a0.w);
    af[4] = (short)f2bf(a1.x); af[5] = (short)f2bf(a1.y);
    af[6] = (short)f2bf(a1.z); af[7] = (short)f2bf(a1.w);
#pragma unroll
    for (int nt = 0; nt < 4; ++nt) {
      uint4 bu = gswz[(nt * 8 + kstep) * 64 + lane];
      short8 bf = *(short8*)&bu;
      acc[nt] = __builtin_amdgcn_mfma_f32_16x16x32_bf16(af, bf, acc[nt], 0, 0, 0);
    }
  }

#pragma unroll
  for (int nt = 0; nt < 4; ++nt) {
#pragma unroll
    for (int r = 0; r < 4; ++r) {
      int orow = rowbase + quad * 4 + r;
      if (orow < M)
        h1[(long long)orow * D_HID + nt * 16 + m] = f2bf(acc[nt][r]);
    }
  }
}

// ---------------------------------------------------------------------------
// Team-vectorized CSR SPMM: TEAM = D/4 lanes per row, uint2 (4 bf16) per lane.
template <int D, bool RELU>
__global__ __launch_bounds__(256) void spmm_csr_kernel(
    const int* __restrict__ rs, const u32* __restrict__ csr,
    const u16* __restrict__ in, const float* __restrict__ bias,
    u16* __restrict__ out, int M) {
  constexpr int TEAM = D / 4;
  const int lt = threadIdx.x % TEAM;
  const int row = blockIdx.x * (256 / TEAM) + threadIdx.x / TEAM;
  if (row >= M) return;
  const int start = (row == 0) ? 0 : rs[row - 1];
  const int end = rs[row];
  const float qs = 1.f / 32768.f;
  const u16* inp = in + lt * 4;

  float a0 = 0.f, a1 = 0.f, a2 = 0.f, a3 = 0.f;
  int j = start;
  for (; j + 4 <= end; j += 4) {
    u32 p0 = csr[j], p1 = csr[j + 1], p2 = csr[j + 2], p3 = csr[j + 3];
    uint2 w0 = *(const uint2*)&inp[(long long)(p0 >> 15) * D];
    uint2 w1 = *(const uint2*)&inp[(long long)(p1 >> 15) * D];
    uint2 w2 = *(const uint2*)&inp[(long long)(p2 >> 15) * D];
    uint2 w3 = *(const uint2*)&inp[(long long)(p3 >> 15) * D];
    float v0 = (float)(p0 & 32767u) * qs;
    float v1 = (float)(p1 & 32767u) * qs;
    float v2 = (float)(p2 & 32767u) * qs;
    float v3 = (float)(p3 & 32767u) * qs;
    a0 = fmaf(v0, bf2f(w0.x), a0); a1 = fmaf(v0, bf2f_hi(w0.x), a1);
    a2 = fmaf(v0, bf2f(w0.y), a2); a3 = fmaf(v0, bf2f_hi(w0.y), a3);
    a0 = fmaf(v1, bf2f(w1.x), a0); a1 = fmaf(v1, bf2f_hi(w1.x), a1);
    a2 = fmaf(v1, bf2f(w1.y), a2); a3 = fmaf(v1, bf2f_hi(w1.y), a3);
    a0 = fmaf(v2, bf2f(w2.x), a0); a1 = fmaf(v2, bf2f_hi(w2.x), a1);
    a2 = fmaf(v2, bf2f(w2.y), a2); a3 = fmaf(v2, bf2f_hi(w2.y), a3);
    a0 = fmaf(v3, bf2f(w3.x), a0); a1 = fmaf(v3, bf2f_hi(w3.x), a1);
    a2 = fmaf(v3, bf2f(w3.y), a2); a3 = fmaf(v3, bf2f_hi(w3.y), a3);
  }
  for (; j < end; ++j) {
    u32 pk = csr[j];
    uint2 w = *(const uint2*)&inp[(long long)(pk >> 15) * D];
    float v = (float)(pk & 32767u) * qs;
    a0 = fmaf(v, bf2f(w.x), a0); a1 = fmaf(v, bf2f_hi(w.x), a1);
    a2 = fmaf(v, bf2f(w.y), a2); a3 = fmaf(v, bf2f_hi(w.y), a3);
  }
  const float4 bv = *(const float4*)&bias[lt * 4];
  a0 += bv.x; a1 += bv.y; a2 += bv.z; a3 += bv.w;
  if (RELU) {
    a0 = fmaxf(a0, 0.f); a1 = fmaxf(a1, 0.f);
    a2 = fmaxf(a2, 0.f); a3 = fmaxf(a3, 0.f);
  }
  uint2 o;
  o.x = (u32)f2bf(a0) | ((u32)f2bf(a1) << 16);
  o.y = (u32)f2bf(a2) | ((u32)f2bf(a3) << 16);
  *(uint2*)&out[(long long)row * D + lt * 4] = o;
}

// ---------------------------------------------------------------------------
// GEMM2: h2[M,32](bf16) = z1[M,64](bf16) @ W2[64,32](f32)
__global__ __launch_bounds__(256) void gemm2_kernel(
    const u16* __restrict__ z1, const float* __restrict__ W2,
    u16* __restrict__ h2, int M) {
  __shared__ float wsm[D_HID * D_EMB];
  const int tid = threadIdx.x;
  for (int i = tid; i < D_HID * D_EMB / 4; i += 256)
    ((float4*)wsm)[i] = ((const float4*)W2)[i];
  __syncthreads();

  const int row = blockIdx.x * 256 + tid;
  if (row >= M) return;

  float4 acc4[8];
  for (int c = 0; c < 8; ++c) acc4[c] = make_float4(0.f, 0.f, 0.f, 0.f);

  const uint4* zr = (const uint4*)&z1[(long long)row * D_HID];
  for (int blk = 0; blk < 8; ++blk) {
    float a8[8];
    unpack8(zr[blk], a8);
    for (int kk = 0; kk < 8; ++kk) {
      const float a = a8[kk];
      const float4* wr = (const float4*)&wsm[(blk * 8 + kk) * D_EMB];
      for (int c = 0; c < 8; ++c) {
        float4 wv = wr[c];
        acc4[c].x += a * wv.x;
        acc4[c].y += a * wv.y;
        acc4[c].z += a * wv.z;
        acc4[c].w += a * wv.w;
      }
    }
  }
  u32 pk[16];
  for (int c = 0; c < 8; ++c) {
    pk[c * 2 + 0] = (u32)f2bf(acc4[c].x) | ((u32)f2bf(acc4[c].y) << 16);
    pk[c * 2 + 1] = (u32)f2bf(acc4[c].z) | ((u32)f2bf(acc4[c].w) << 16);
  }
  uint4* op = (uint4*)&h2[(long long)row * D_EMB];
  op[0] = make_uint4(pk[0], pk[1], pk[2], pk[3]);
  op[1] = make_uint4(pk[4], pk[5], pk[6], pk[7]);
  op[2] = make_uint4(pk[8], pk[9], pk[10], pk[11]);
  op[3] = make_uint4(pk[12], pk[13], pk[14], pk[15]);
}

// ---------------------------------------------------------------------------
// Decoder: scores[e] = dot(z2[src], z2[dst])  (bf16 rows, fp32 dot)
__global__ __launch_bounds__(256) void decode_kernel(
    const int* __restrict__ ei, const u16* __restrict__ z2,
    float* __restrict__ out, int nE) {
  const int e = blockIdx.x * 256 + threadIdx.x;
  if (e >= nE) return;
  const int s = ei[e];
  const int d = ei[nE + e];
  const uint4* za = (const uint4*)&z2[(long long)s * D_EMB];
  const uint4* zb = (const uint4*)&z2[(long long)d * D_EMB];
  float acc = 0.f;
  for (int c = 0; c < 4; ++c) {
    float a8[8], b8[8];
    unpack8(za[c], a8);
    unpack8(zb[c], b8);
    for (int k = 0; k < 8; ++k) acc = fmaf(a8[k], b8[k], acc);
  }
  out[e] = acc;
}

// ---------------------------------------------------------------------------
extern "C" void kernel_launch(void* const* d_in, const int* in_sizes, int n_in,
                              void* d_out, int out_size, void* d_ws, size_t ws_size,
                              hipStream_t stream) {
  const float* x       = (const float*)d_in[0];
  const int*   adj_src = (const int*)d_in[1];
  const int*   adj_dst = (const int*)d_in[2];
  const float* adj_val = (const float*)d_in[3];
  const int*   ei      = (const int*)d_in[4];
  const float* W1      = (const float*)d_in[5];
  const float* b1      = (const float*)d_in[6];
  const float* W2      = (const float*)d_in[7];
  const float* b2      = (const float*)d_in[8];

  const int M   = in_sizes[0] / D_IN;      // 100000
  const int nnz = in_sizes[1];             // 3200000
  const int nE  = in_sizes[4] / 2;         // 2000000

  const int NB = (M + SCAN_ELEMS - 1) / SCAN_ELEMS;  // 98 (must be <= 256)

  // Workspace:
  //   [0, 12.8):     csr packed u32
  //   [12.8, 25.6):  h1 bf16 (h2 reuses)
  //   [25.6, 38.4):  z1 bf16 (z2 reuses)
  //   [60.0, +32KB): gswz (pre-swizzled W1 bf16 fragments)
  char* ws = (char*)d_ws;
  u32*   csr  = (u32*)(ws);
  u16*   h1   = (u16*)(ws + (size_t)nnz * 4);
  u16*   z1   = (u16*)(ws + (size_t)nnz * 4 + (size_t)M * D_HID * 2);
  u16*   h2   = h1;
  u16*   z2   = z1;
  uint4* gswz = (uint4*)(ws + 60ull * 1024 * 1024);

  // Small scratch in d_out (8 MB, dead until decode):
  int* rs     = (int*)d_out;                 // M ints
  int* rowcnt = (int*)d_out + 128 * 1024;    // M ints
  int* cur    = (int*)d_out + 256 * 1024;    // M ints
  int* bsum   = (int*)d_out + 384 * 1024;    // NB ints

  // --- W1 swizzle ---
  w1_swizzle_kernel<<<8, 256, 0, stream>>>(W1, gswz);

  // --- COO -> CSR (direct scatter) ---
  hipMemsetAsync(rowcnt, 0, (size_t)M * 4, stream);
  hist_kernel<<<2048, 256, 0, stream>>>(adj_dst, rowcnt, nnz);
  scan_blocksum_kernel<<<NB, 256, 0, stream>>>(rowcnt, bsum, M);
  scan_write_kernel<<<NB, 256, 0, stream>>>(rowcnt, bsum, rs, cur, M, NB);
  scatter_kernel<<<2048, 256, 0, stream>>>(adj_src, adj_dst, adj_val, cur, csr, nnz);

  // --- GEMM1 via MFMA ---
  gemm1_mfma_kernel<<<(M + 63) / 64, 256, 0, stream>>>(x, gswz, h1, M);

  // --- SPMM1 + b1 + ReLU (16-lane teams) ---
  spmm_csr_kernel<D_HID, true><<<(M + 15) / 16, 256, 0, stream>>>(
      rs, csr, h1, b1, z1, M);

  // --- GEMM2 ---
  gemm2_kernel<<<(M + 255) / 256, 256, 0, stream>>>(z1, W2, h2, M);

  // --- SPMM2 + b2 (8-lane teams) ---
  spmm_csr_kernel<D_EMB, false><<<(M + 31) / 32, 256, 0, stream>>>(
      rs, csr, h2, b2, z2, M);

  // --- Decode (overwrites d_out scratch) ---
  decode_kernel<<<(nE + 255) / 256, 256, 0, stream>>>(ei, z2, (float*)d_out, nE);
}

// Round 2
// 437.484 us; speedup vs baseline: 1.6122x; 1.6122x over previous
//
#include <hip/hip_runtime.h>
#include <hip/hip_bf16.h>

// GCN link predictor, Round 11: revert to R9's LDS-staged bucketed sort
// (R10 lesson: random 4B global scatter costs a 64B line writeback per store
// -> 196MB WRITE, 280us. LDS-staged partition + bucket-local sort is the
// right structure; measured sort pipeline is only ~25-35us total).
// R11 delta vs R9: SPMM inner loop loads csr via ALIGNED uint4 (head/tail
// peel) instead of 4 scalar dword broadcasts (-37% VMEM instr in hot loop),
// and all gather addressing is 32-bit shifts instead of 64-bit multiplies
// (SPMM + decode). Everything else is verbatim R9 (431.7us verified).

#define D_IN  256
#define D_HID 64
#define D_EMB 32
#define BROWS 256       // dst-rows per bucket
#define NBUK_MAX 512    // >= ceil(M/BROWS) = 391
#define TILE  4096      // edges per partition tile
#define PBS   512       // partition block size (PER = 8)
#define SBS   1024      // bucket_sort block size

typedef unsigned short u16;
typedef unsigned int u32;
typedef __attribute__((ext_vector_type(8))) short short8;   // 8 bf16
typedef __attribute__((ext_vector_type(4))) float f32x4;

__device__ __forceinline__ float bf2f(u32 u) {
  return __uint_as_float((u & 0xFFFFu) << 16);
}
__device__ __forceinline__ float bf2f_hi(u32 u) {
  return __uint_as_float(u & 0xFFFF0000u);
}
__device__ __forceinline__ u16 f2bf(float f) {
  u32 x = __float_as_uint(f);
  x += 0x7FFFu + ((x >> 16) & 1u);  // RNE
  return (u16)(x >> 16);
}
__device__ __forceinline__ void unpack8(uint4 u, float* f) {
  f[0] = bf2f(u.x); f[1] = bf2f(u.x >> 16);
  f[2] = bf2f(u.y); f[3] = bf2f(u.y >> 16);
  f[4] = bf2f(u.z); f[5] = bf2f(u.z >> 16);
  f[6] = bf2f(u.w); f[7] = bf2f(u.w >> 16);
}

// ---------------------------------------------------------------------------
// One-time W1 swizzle: fp32 [256,64] -> bf16 B-fragments.
__global__ __launch_bounds__(256) void w1_swizzle_kernel(
    const float* __restrict__ W1, uint4* __restrict__ gswz) {
  const int s = blockIdx.x * 256 + threadIdx.x;  // 2048 slots
  const int lane = s & 63;
  const int kstep = (s >> 6) & 7;
  const int nt = s >> 9;
  const int col = nt * 16 + (lane & 15);
  const int kbase = kstep * 32 + (lane >> 4) * 8;
  u32 p[4];
  for (int jp = 0; jp < 4; ++jp) {
    u32 lo = f2bf(W1[(kbase + 2 * jp) * D_HID + col]);
    u32 hi = f2bf(W1[(kbase + 2 * jp + 1) * D_HID + col]);
    p[jp] = lo | (hi << 16);
  }
  gswz[s] = make_uint4(p[0], p[1], p[2], p[3]);
}

// ---------------------------------------------------------------------------
// Bucket histogram (LDS-staged).
__global__ __launch_bounds__(256) void bin_count(
    const int* __restrict__ dst, int* __restrict__ hist, int nnz, int nbuk) {
  __shared__ int h[NBUK_MAX];
  for (int i = threadIdx.x; i < nbuk; i += 256) h[i] = 0;
  __syncthreads();
  const int stride = gridDim.x * 256;
  for (int e = blockIdx.x * 256 + threadIdx.x; e < nnz; e += stride)
    atomicAdd(&h[dst[e] >> 8], 1);
  __syncthreads();
  for (int i = threadIdx.x; i < nbuk; i += 256) {
    int v = h[i];
    if (v) atomicAdd(&hist[i], v);
  }
}

// 1-block exclusive scan (in place), copy to cur, sentinel hist[n] = total.
__global__ __launch_bounds__(256) void bin_scan(
    int* __restrict__ hist, int* __restrict__ cur, int n) {
  __shared__ int sm[256];
  const int t = threadIdx.x;
  const int per = (n + 255) / 256;
  const int base = t * per;
  int loc[4];
  int s = 0;
  for (int i = 0; i < per; ++i) {
    int idx = base + i;
    int v = (idx < n) ? hist[idx] : 0;
    loc[i] = s;
    s += v;
  }
  sm[t] = s;
  __syncthreads();
  for (int off = 1; off < 256; off <<= 1) {
    int tmp = (t >= off) ? sm[t - off] : 0;
    __syncthreads();
    sm[t] += tmp;
    __syncthreads();
  }
  const int b0 = sm[t] - s;
  for (int i = 0; i < per; ++i) {
    int idx = base + i;
    if (idx < n) {
      int p = b0 + loc[i];
      hist[idx] = p;
      cur[idx] = p;
    }
  }
  if (t == 255) hist[n] = sm[255];
}

// ---------------------------------------------------------------------------
// Tile-staged partition, 512 threads, 40KB LDS => 4 blocks/CU (32 waves).
// payload: .x = src<<8 | dstlow, .y = bucket<<15 | q15(val).
__global__ __launch_bounds__(PBS) void partition_kernel(
    const int* __restrict__ src, const int* __restrict__ dst,
    const float* __restrict__ val, int* __restrict__ cur,
    int2* __restrict__ payload, int nnz, int nbuk) {
  __shared__ int2 stage[TILE];            // 32 KB
  __shared__ int hist[NBUK_MAX];          // 2 KB: counts -> local excl offsets
  __shared__ int lcur[NBUK_MAX];          // 2 KB
  __shared__ int gbase[NBUK_MAX];         // 2 KB
  __shared__ int sm[PBS];                 // 2 KB

  const int t = threadIdx.x;
  const long long base = (long long)blockIdx.x * TILE;
  const int cnt = min(TILE, (int)(nnz - base));

  for (int i = t; i < nbuk; i += PBS) hist[i] = 0;
  __syncthreads();

  constexpr int PER = TILE / PBS;  // 8
  int key[PER], vq[PER];
  short bk[PER];
  for (int i = 0; i < PER; ++i) {
    int idx = t + i * PBS;
    if (idx < cnt) {
      int d = dst[base + idx];
      int b = d >> 8;
      bk[i] = (short)b;
      key[i] = (src[base + idx] << 8) | (d & (BROWS - 1));
      int q = (int)(val[base + idx] * 32768.f + 0.5f);
      q = min(q, 32767);
      vq[i] = (b << 15) | q;
      atomicAdd(&hist[b], 1);
    } else {
      bk[i] = -1;
    }
  }
  __syncthreads();

  // scan hist (nbuk <= PBS) -> exclusive offsets; reserve global chunks
  {
    int c = (t < nbuk) ? hist[t] : 0;
    sm[t] = c;
    __syncthreads();
    for (int off = 1; off < PBS; off <<= 1) {
      int tmp = (t >= off) ? sm[t - off] : 0;
      __syncthreads();
      sm[t] += tmp;
      __syncthreads();
    }
    int excl = sm[t] - c;
    if (t < nbuk) {
      hist[t] = excl;
      lcur[t] = excl;
      if (c > 0) gbase[t] = atomicAdd(&cur[t], c);
    }
  }
  __syncthreads();

  // counting sort into stage
  for (int i = 0; i < PER; ++i) {
    if (bk[i] >= 0) {
      int p = atomicAdd(&lcur[bk[i]], 1);
      stage[p] = make_int2(key[i], vq[i]);
    }
  }
  __syncthreads();

  // contiguous run write-out (bucket recovered from .y)
  for (int i = t; i < cnt; i += PBS) {
    int2 pk = stage[i];
    int b = pk.y >> 15;
    payload[gbase[b] + (i - hist[b])] = pk;
  }
}

// ---------------------------------------------------------------------------
// Bucket-local counting sort -> 4B packed CSR (src:17 | q15) + inclusive rs.
// 1024 threads/block; scan by first 256 lanes.
__global__ __launch_bounds__(SBS) void bucket_sort_kernel(
    const int* __restrict__ bscan, const int2* __restrict__ payload,
    u32* __restrict__ csr, int* __restrict__ rs, int M) {
  __shared__ int cnt_s[BROWS];
  __shared__ int sm[BROWS];
  const int b = blockIdx.x;
  const int t = threadIdx.x;
  const int start = bscan[b];
  const int end = bscan[b + 1];

  if (t < BROWS) cnt_s[t] = 0;
  __syncthreads();
  for (int j = start + t; j < end; j += SBS)
    atomicAdd(&cnt_s[payload[j].x & (BROWS - 1)], 1);
  __syncthreads();

  int v = 0;
  if (t < BROWS) { v = cnt_s[t]; sm[t] = v; }
  __syncthreads();
  for (int off = 1; off < BROWS; off <<= 1) {
    int tmp = 0;
    if (t < BROWS && t >= off) tmp = sm[t - off];
    __syncthreads();
    if (t < BROWS) sm[t] += tmp;
    __syncthreads();
  }
  if (t < BROWS) {
    int row = b * BROWS + t;
    if (row < M) rs[row] = start + sm[t];    // inclusive row end
    cnt_s[t] = start + sm[t] - v;            // exclusive cursor
  }
  __syncthreads();

  for (int j = start + t; j < end; j += SBS) {
    int2 pk = payload[j];
    int r = pk.x & (BROWS - 1);
    int p = atomicAdd(&cnt_s[r], 1);
    csr[p] = ((u32)(pk.x >> 8) << 15) | (u32)(pk.y & 32767);
  }
}

// ---------------------------------------------------------------------------
// GEMM1 via MFMA: h1[M,64](bf16) = x[M,256](f32 -> bf16) @ W1.
__global__ __launch_bounds__(256) void gemm1_mfma_kernel(
    const float* __restrict__ x, const uint4* __restrict__ gswz,
    u16* __restrict__ h1, int M) {
  const int tid = threadIdx.x;
  const int wv = tid >> 6;
  const int lane = tid & 63;
  const int quad = lane >> 4;
  const int m = lane & 15;

  const int rowbase = blockIdx.x * 64 + wv * 16;
  int arow = rowbase + m;
  if (arow >= M) arow = M - 1;

  f32x4 acc[4];
  for (int nt = 0; nt < 4; ++nt) acc[nt] = (f32x4){0.f, 0.f, 0.f, 0.f};

  const float* xrow = &x[(long long)arow * D_IN];

#pragma unroll
  for (int kstep = 0; kstep < 8; ++kstep) {
    const int kbase = kstep * 32 + quad * 8;
    float4 a0 = *(const float4*)&xrow[kbase];
    float4 a1 = *(const float4*)&xrow[kbase + 4];
    short8 af;
    af[0] = (short)f2bf(a0.x); af[1] = (short)f2bf(a0.y);
    af[2] = (short)f2bf(a0.z); af[3] = (short)f2bf(a0.w);
    af[4] = (short)f2bf(a1.x); af[5] = (short)f2bf(a1.y);
    af[6] = (short)f2bf(a1.z); af[7] = (short)f2bf(a1.w);
#pragma unroll
    for (int nt = 0; nt < 4; ++nt) {
      uint4 bu = gswz[(nt * 8 + kstep) * 64 + lane];
      short8 bf = *(short8*)&bu;
      acc[nt] = __builtin_amdgcn_mfma_f32_16x16x32_bf16(af, bf, acc[nt], 0, 0, 0);
    }
  }

#pragma unroll
  for (int nt = 0; nt < 4; ++nt) {
#pragma unroll
    for (int r = 0; r < 4; ++r) {
      int orow = rowbase + quad * 4 + r;
      if (orow < M)
        h1[(long long)orow * D_HID + nt * 16 + m] = f2bf(acc[nt][r]);
    }
  }
}

// ---------------------------------------------------------------------------
// Team-vectorized CSR SPMM: TEAM = D/4 lanes per row, uint2 (4 bf16) per lane.
// R11: csr read via aligned uint4 (head/tail peel); 32-bit shift addressing.
template <int D, bool RELU>
__global__ __launch_bounds__(256) void spmm_csr_kernel(
    const int* __restrict__ rs, const u32* __restrict__ csr,
    const u16* __restrict__ in, const float* __restrict__ bias,
    u16* __restrict__ out, int M) {
  constexpr int TEAM = D / 4;
  constexpr int SH = (D == 64) ? 6 : 5;   // u16 elems per row = D = 1<<SH
  const int lt = threadIdx.x % TEAM;
  const int row = blockIdx.x * (256 / TEAM) + threadIdx.x / TEAM;
  if (row >= M) return;
  const int start = (row == 0) ? 0 : rs[row - 1];
  const int end = rs[row];
  const float qs = 1.f / 32768.f;
  const u16* inp = in + lt * 4;

  float a0 = 0.f, a1 = 0.f, a2 = 0.f, a3 = 0.f;
  int j = start;

  // head peel to 16B-aligned csr index
  int head = (4 - (start & 3)) & 3;
  if (head > end - start) head = end - start;
  for (int h = 0; h < head; ++h, ++j) {
    u32 pk = csr[j];
    uint2 w = *(const uint2*)(inp + ((pk >> 15) << SH));
    float v = (float)(pk & 32767u) * qs;
    a0 = fmaf(v, bf2f(w.x), a0); a1 = fmaf(v, bf2f_hi(w.x), a1);
    a2 = fmaf(v, bf2f(w.y), a2); a3 = fmaf(v, bf2f_hi(w.y), a3);
  }

  for (; j + 4 <= end; j += 4) {
    uint4 p = *(const uint4*)&csr[j];
    uint2 w0 = *(const uint2*)(inp + ((p.x >> 15) << SH));
    uint2 w1 = *(const uint2*)(inp + ((p.y >> 15) << SH));
    uint2 w2 = *(const uint2*)(inp + ((p.z >> 15) << SH));
    uint2 w3 = *(const uint2*)(inp + ((p.w >> 15) << SH));
    float v0 = (float)(p.x & 32767u) * qs;
    float v1 = (float)(p.y & 32767u) * qs;
    float v2 = (float)(p.z & 32767u) * qs;
    float v3 = (float)(p.w & 32767u) * qs;
    a0 = fmaf(v0, bf2f(w0.x), a0); a1 = fmaf(v0, bf2f_hi(w0.x), a1);
    a2 = fmaf(v0, bf2f(w0.y), a2); a3 = fmaf(v0, bf2f_hi(w0.y), a3);
    a0 = fmaf(v1, bf2f(w1.x), a0); a1 = fmaf(v1, bf2f_hi(w1.x), a1);
    a2 = fmaf(v1, bf2f(w1.y), a2); a3 = fmaf(v1, bf2f_hi(w1.y), a3);
    a0 = fmaf(v2, bf2f(w2.x), a0); a1 = fmaf(v2, bf2f_hi(w2.x), a1);
    a2 = fmaf(v2, bf2f(w2.y), a2); a3 = fmaf(v2, bf2f_hi(w2.y), a3);
    a0 = fmaf(v3, bf2f(w3.x), a0); a1 = fmaf(v3, bf2f_hi(w3.x), a1);
    a2 = fmaf(v3, bf2f(w3.y), a2); a3 = fmaf(v3, bf2f_hi(w3.y), a3);
  }
  for (; j < end; ++j) {
    u32 pk = csr[j];
    uint2 w = *(const uint2*)(inp + ((pk >> 15) << SH));
    float v = (float)(pk & 32767u) * qs;
    a0 = fmaf(v, bf2f(w.x), a0); a1 = fmaf(v, bf2f_hi(w.x), a1);
    a2 = fmaf(v, bf2f(w.y), a2); a3 = fmaf(v, bf2f_hi(w.y), a3);
  }
  const float4 bv = *(const float4*)&bias[lt * 4];
  a0 += bv.x; a1 += bv.y; a2 += bv.z; a3 += bv.w;
  if (RELU) {
    a0 = fmaxf(a0, 0.f); a1 = fmaxf(a1, 0.f);
    a2 = fmaxf(a2, 0.f); a3 = fmaxf(a3, 0.f);
  }
  uint2 o;
  o.x = (u32)f2bf(a0) | ((u32)f2bf(a1) << 16);
  o.y = (u32)f2bf(a2) | ((u32)f2bf(a3) << 16);
  *(uint2*)&out[((u32)row << SH) + lt * 4] = o;
}

// ---------------------------------------------------------------------------
// GEMM2: h2[M,32](bf16) = z1[M,64](bf16) @ W2[64,32](f32)
__global__ __launch_bounds__(256) void gemm2_kernel(
    const u16* __restrict__ z1, const float* __restrict__ W2,
    u16* __restrict__ h2, int M) {
  __shared__ float wsm[D_HID * D_EMB];
  const int tid = threadIdx.x;
  for (int i = tid; i < D_HID * D_EMB / 4; i += 256)
    ((float4*)wsm)[i] = ((const float4*)W2)[i];
  __syncthreads();

  const int row = blockIdx.x * 256 + tid;
  if (row >= M) return;

  float4 acc4[8];
  for (int c = 0; c < 8; ++c) acc4[c] = make_float4(0.f, 0.f, 0.f, 0.f);

  const uint4* zr = (const uint4*)&z1[(long long)row * D_HID];
  for (int blk = 0; blk < 8; ++blk) {
    float a8[8];
    unpack8(zr[blk], a8);
    for (int kk = 0; kk < 8; ++kk) {
      const float a = a8[kk];
      const float4* wr = (const float4*)&wsm[(blk * 8 + kk) * D_EMB];
      for (int c = 0; c < 8; ++c) {
        float4 wv = wr[c];
        acc4[c].x += a * wv.x;
        acc4[c].y += a * wv.y;
        acc4[c].z += a * wv.z;
        acc4[c].w += a * wv.w;
      }
    }
  }
  u32 pk[16];
  for (int c = 0; c < 8; ++c) {
    pk[c * 2 + 0] = (u32)f2bf(acc4[c].x) | ((u32)f2bf(acc4[c].y) << 16);
    pk[c * 2 + 1] = (u32)f2bf(acc4[c].z) | ((u32)f2bf(acc4[c].w) << 16);
  }
  uint4* op = (uint4*)&h2[(long long)row * D_EMB];
  op[0] = make_uint4(pk[0], pk[1], pk[2], pk[3]);
  op[1] = make_uint4(pk[4], pk[5], pk[6], pk[7]);
  op[2] = make_uint4(pk[8], pk[9], pk[10], pk[11]);
  op[3] = make_uint4(pk[12], pk[13], pk[14], pk[15]);
}

// ---------------------------------------------------------------------------
// Decoder: scores[e] = dot(z2[src], z2[dst])  (bf16 rows, fp32 dot)
__global__ __launch_bounds__(256) void decode_kernel(
    const int* __restrict__ ei, const u16* __restrict__ z2,
    float* __restrict__ out, int nE) {
  const int e = blockIdx.x * 256 + threadIdx.x;
  if (e >= nE) return;
  const u32 s = (u32)ei[e];
  const u32 d = (u32)ei[nE + e];
  const uint4* za = (const uint4*)(z2 + (s << 5));
  const uint4* zb = (const uint4*)(z2 + (d << 5));
  float acc = 0.f;
  for (int c = 0; c < 4; ++c) {
    float a8[8], b8[8];
    unpack8(za[c], a8);
    unpack8(zb[c], b8);
    for (int k = 0; k < 8; ++k) acc = fmaf(a8[k], b8[k], acc);
  }
  out[e] = acc;
}

// ---------------------------------------------------------------------------
extern "C" void kernel_launch(void* const* d_in, const int* in_sizes, int n_in,
                              void* d_out, int out_size, void* d_ws, size_t ws_size,
                              hipStream_t stream) {
  const float* x       = (const float*)d_in[0];
  const int*   adj_src = (const int*)d_in[1];
  const int*   adj_dst = (const int*)d_in[2];
  const float* adj_val = (const float*)d_in[3];
  const int*   ei      = (const int*)d_in[4];
  const float* W1      = (const float*)d_in[5];
  const float* b1      = (const float*)d_in[6];
  const float* W2      = (const float*)d_in[7];
  const float* b2      = (const float*)d_in[8];

  const int M   = in_sizes[0] / D_IN;      // 100000
  const int nnz = in_sizes[1];             // 3200000
  const int nE  = in_sizes[4] / 2;         // 2000000

  const int NBUK = (M + BROWS - 1) / BROWS;  // 391

  // Workspace (76.8 MB):
  //   [0, 12.8):     csr packed u32
  //   [12.8, 38.4):  payload int2 (dead after sort) -> h1 bf16, h2 reuse
  //   [38.4, 51.2):  z1 bf16, z2 reuse
  //   [60.0, +32KB): gswz (pre-swizzled W1 bf16 fragments)
  char* ws = (char*)d_ws;
  u32*   csr     = (u32*)(ws);
  int2*  payload = (int2*)(ws + (size_t)nnz * 4);
  u16*   h1      = (u16*)(ws + (size_t)nnz * 4);
  u16*   z1      = (u16*)(ws + (size_t)nnz * 4 + (size_t)nnz * 8);
  u16*   h2      = h1;
  u16*   z2      = z1;
  uint4* gswz    = (uint4*)(ws + 60ull * 1024 * 1024);

  // Small scratch in d_out (8 MB, dead until decode):
  int* rs    = (int*)d_out;                 // M ints
  int* bscan = (int*)d_out + 112 * 1024;    // NBUK+1 ints
  int* cur   = (int*)d_out + 120 * 1024;    // NBUK ints

  // --- W1 swizzle ---
  w1_swizzle_kernel<<<8, 256, 0, stream>>>(W1, gswz);

  // --- bucket partition ---
  hipMemsetAsync(bscan, 0, (size_t)(NBUK + 1) * 4, stream);
  bin_count<<<256, 256, 0, stream>>>(adj_dst, bscan, nnz, NBUK);
  bin_scan<<<1, 256, 0, stream>>>(bscan, cur, NBUK);
  partition_kernel<<<(nnz + TILE - 1) / TILE, PBS, 0, stream>>>(
      adj_src, adj_dst, adj_val, cur, payload, nnz, NBUK);

  // --- bucket-local counting sort -> packed CSR + rs ---
  bucket_sort_kernel<<<NBUK, SBS, 0, stream>>>(bscan, payload, csr, rs, M);

  // --- GEMM1 via MFMA ---
  gemm1_mfma_kernel<<<(M + 63) / 64, 256, 0, stream>>>(x, gswz, h1, M);

  // --- SPMM1 + b1 + ReLU (16-lane teams) ---
  spmm_csr_kernel<D_HID, true><<<(M + 15) / 16, 256, 0, stream>>>(
      rs, csr, h1, b1, z1, M);

  // --- GEMM2 ---
  gemm2_kernel<<<(M + 255) / 256, 256, 0, stream>>>(z1, W2, h2, M);

  // --- SPMM2 + b2 (8-lane teams) ---
  spmm_csr_kernel<D_EMB, false><<<(M + 31) / 32, 256, 0, stream>>>(
      rs, csr, h2, b2, z2, M);

  // --- Decode (overwrites d_out scratch) ---
  decode_kernel<<<(nE + 255) / 256, 256, 0, stream>>>(ei, z2, (float*)d_out, nE);
}

// Round 3
// 433.585 us; speedup vs baseline: 1.6267x; 1.0090x over previous
//
#include <hip/hip_runtime.h>
#include <hip/hip_bf16.h>

// GCN link predictor, Round 12: attack gather latency with MLP.
// R11 postmortem: spmm1 is now the top kernel (62us, FETCH 156MB = 2.8TB/s,
// VALUBusy 39%, Occ 66%) -> neither BW- nor VALU-bound: latency-bound on the
// csr->gather dependent chain with only 4 outstanding gathers per lane.
// R12: (a) SPMM inner loop unrolled to 8 edges (2 independent uint4 csr loads
// + 8 row-gathers in flight before the FMA block); (b) decode processes 2
// edges per thread (8 uint4 gathers in flight, int2 ei loads).
// Sort pipeline / GEMMs / layout verbatim from R11 (R9 structure).

#define D_IN  256
#define D_HID 64
#define D_EMB 32
#define BROWS 256       // dst-rows per bucket
#define NBUK_MAX 512    // >= ceil(M/BROWS) = 391
#define TILE  4096      // edges per partition tile
#define PBS   512       // partition block size (PER = 8)
#define SBS   1024      // bucket_sort block size

typedef unsigned short u16;
typedef unsigned int u32;
typedef __attribute__((ext_vector_type(8))) short short8;   // 8 bf16
typedef __attribute__((ext_vector_type(4))) float f32x4;

__device__ __forceinline__ float bf2f(u32 u) {
  return __uint_as_float((u & 0xFFFFu) << 16);
}
__device__ __forceinline__ float bf2f_hi(u32 u) {
  return __uint_as_float(u & 0xFFFF0000u);
}
__device__ __forceinline__ u16 f2bf(float f) {
  u32 x = __float_as_uint(f);
  x += 0x7FFFu + ((x >> 16) & 1u);  // RNE
  return (u16)(x >> 16);
}
__device__ __forceinline__ void unpack8(uint4 u, float* f) {
  f[0] = bf2f(u.x); f[1] = bf2f(u.x >> 16);
  f[2] = bf2f(u.y); f[3] = bf2f(u.y >> 16);
  f[4] = bf2f(u.z); f[5] = bf2f(u.z >> 16);
  f[6] = bf2f(u.w); f[7] = bf2f(u.w >> 16);
}

// ---------------------------------------------------------------------------
// One-time W1 swizzle: fp32 [256,64] -> bf16 B-fragments.
__global__ __launch_bounds__(256) void w1_swizzle_kernel(
    const float* __restrict__ W1, uint4* __restrict__ gswz) {
  const int s = blockIdx.x * 256 + threadIdx.x;  // 2048 slots
  const int lane = s & 63;
  const int kstep = (s >> 6) & 7;
  const int nt = s >> 9;
  const int col = nt * 16 + (lane & 15);
  const int kbase = kstep * 32 + (lane >> 4) * 8;
  u32 p[4];
  for (int jp = 0; jp < 4; ++jp) {
    u32 lo = f2bf(W1[(kbase + 2 * jp) * D_HID + col]);
    u32 hi = f2bf(W1[(kbase + 2 * jp + 1) * D_HID + col]);
    p[jp] = lo | (hi << 16);
  }
  gswz[s] = make_uint4(p[0], p[1], p[2], p[3]);
}

// ---------------------------------------------------------------------------
// Bucket histogram (LDS-staged).
__global__ __launch_bounds__(256) void bin_count(
    const int* __restrict__ dst, int* __restrict__ hist, int nnz, int nbuk) {
  __shared__ int h[NBUK_MAX];
  for (int i = threadIdx.x; i < nbuk; i += 256) h[i] = 0;
  __syncthreads();
  const int stride = gridDim.x * 256;
  for (int e = blockIdx.x * 256 + threadIdx.x; e < nnz; e += stride)
    atomicAdd(&h[dst[e] >> 8], 1);
  __syncthreads();
  for (int i = threadIdx.x; i < nbuk; i += 256) {
    int v = h[i];
    if (v) atomicAdd(&hist[i], v);
  }
}

// 1-block exclusive scan (in place), copy to cur, sentinel hist[n] = total.
__global__ __launch_bounds__(256) void bin_scan(
    int* __restrict__ hist, int* __restrict__ cur, int n) {
  __shared__ int sm[256];
  const int t = threadIdx.x;
  const int per = (n + 255) / 256;
  const int base = t * per;
  int loc[4];
  int s = 0;
  for (int i = 0; i < per; ++i) {
    int idx = base + i;
    int v = (idx < n) ? hist[idx] : 0;
    loc[i] = s;
    s += v;
  }
  sm[t] = s;
  __syncthreads();
  for (int off = 1; off < 256; off <<= 1) {
    int tmp = (t >= off) ? sm[t - off] : 0;
    __syncthreads();
    sm[t] += tmp;
    __syncthreads();
  }
  const int b0 = sm[t] - s;
  for (int i = 0; i < per; ++i) {
    int idx = base + i;
    if (idx < n) {
      int p = b0 + loc[i];
      hist[idx] = p;
      cur[idx] = p;
    }
  }
  if (t == 255) hist[n] = sm[255];
}

// ---------------------------------------------------------------------------
// Tile-staged partition, 512 threads, 40KB LDS => 4 blocks/CU (32 waves).
// payload: .x = src<<8 | dstlow, .y = bucket<<15 | q15(val).
__global__ __launch_bounds__(PBS) void partition_kernel(
    const int* __restrict__ src, const int* __restrict__ dst,
    const float* __restrict__ val, int* __restrict__ cur,
    int2* __restrict__ payload, int nnz, int nbuk) {
  __shared__ int2 stage[TILE];            // 32 KB
  __shared__ int hist[NBUK_MAX];          // 2 KB: counts -> local excl offsets
  __shared__ int lcur[NBUK_MAX];          // 2 KB
  __shared__ int gbase[NBUK_MAX];         // 2 KB
  __shared__ int sm[PBS];                 // 2 KB

  const int t = threadIdx.x;
  const long long base = (long long)blockIdx.x * TILE;
  const int cnt = min(TILE, (int)(nnz - base));

  for (int i = t; i < nbuk; i += PBS) hist[i] = 0;
  __syncthreads();

  constexpr int PER = TILE / PBS;  // 8
  int key[PER], vq[PER];
  short bk[PER];
  for (int i = 0; i < PER; ++i) {
    int idx = t + i * PBS;
    if (idx < cnt) {
      int d = dst[base + idx];
      int b = d >> 8;
      bk[i] = (short)b;
      key[i] = (src[base + idx] << 8) | (d & (BROWS - 1));
      int q = (int)(val[base + idx] * 32768.f + 0.5f);
      q = min(q, 32767);
      vq[i] = (b << 15) | q;
      atomicAdd(&hist[b], 1);
    } else {
      bk[i] = -1;
    }
  }
  __syncthreads();

  // scan hist (nbuk <= PBS) -> exclusive offsets; reserve global chunks
  {
    int c = (t < nbuk) ? hist[t] : 0;
    sm[t] = c;
    __syncthreads();
    for (int off = 1; off < PBS; off <<= 1) {
      int tmp = (t >= off) ? sm[t - off] : 0;
      __syncthreads();
      sm[t] += tmp;
      __syncthreads();
    }
    int excl = sm[t] - c;
    if (t < nbuk) {
      hist[t] = excl;
      lcur[t] = excl;
      if (c > 0) gbase[t] = atomicAdd(&cur[t], c);
    }
  }
  __syncthreads();

  // counting sort into stage
  for (int i = 0; i < PER; ++i) {
    if (bk[i] >= 0) {
      int p = atomicAdd(&lcur[bk[i]], 1);
      stage[p] = make_int2(key[i], vq[i]);
    }
  }
  __syncthreads();

  // contiguous run write-out (bucket recovered from .y)
  for (int i = t; i < cnt; i += PBS) {
    int2 pk = stage[i];
    int b = pk.y >> 15;
    payload[gbase[b] + (i - hist[b])] = pk;
  }
}

// ---------------------------------------------------------------------------
// Bucket-local counting sort -> 4B packed CSR (src:17 | q15) + inclusive rs.
// 1024 threads/block; scan by first 256 lanes.
__global__ __launch_bounds__(SBS) void bucket_sort_kernel(
    const int* __restrict__ bscan, const int2* __restrict__ payload,
    u32* __restrict__ csr, int* __restrict__ rs, int M) {
  __shared__ int cnt_s[BROWS];
  __shared__ int sm[BROWS];
  const int b = blockIdx.x;
  const int t = threadIdx.x;
  const int start = bscan[b];
  const int end = bscan[b + 1];

  if (t < BROWS) cnt_s[t] = 0;
  __syncthreads();
  for (int j = start + t; j < end; j += SBS)
    atomicAdd(&cnt_s[payload[j].x & (BROWS - 1)], 1);
  __syncthreads();

  int v = 0;
  if (t < BROWS) { v = cnt_s[t]; sm[t] = v; }
  __syncthreads();
  for (int off = 1; off < BROWS; off <<= 1) {
    int tmp = 0;
    if (t < BROWS && t >= off) tmp = sm[t - off];
    __syncthreads();
    if (t < BROWS) sm[t] += tmp;
    __syncthreads();
  }
  if (t < BROWS) {
    int row = b * BROWS + t;
    if (row < M) rs[row] = start + sm[t];    // inclusive row end
    cnt_s[t] = start + sm[t] - v;            // exclusive cursor
  }
  __syncthreads();

  for (int j = start + t; j < end; j += SBS) {
    int2 pk = payload[j];
    int r = pk.x & (BROWS - 1);
    int p = atomicAdd(&cnt_s[r], 1);
    csr[p] = ((u32)(pk.x >> 8) << 15) | (u32)(pk.y & 32767);
  }
}

// ---------------------------------------------------------------------------
// GEMM1 via MFMA: h1[M,64](bf16) = x[M,256](f32 -> bf16) @ W1.
__global__ __launch_bounds__(256) void gemm1_mfma_kernel(
    const float* __restrict__ x, const uint4* __restrict__ gswz,
    u16* __restrict__ h1, int M) {
  const int tid = threadIdx.x;
  const int wv = tid >> 6;
  const int lane = tid & 63;
  const int quad = lane >> 4;
  const int m = lane & 15;

  const int rowbase = blockIdx.x * 64 + wv * 16;
  int arow = rowbase + m;
  if (arow >= M) arow = M - 1;

  f32x4 acc[4];
  for (int nt = 0; nt < 4; ++nt) acc[nt] = (f32x4){0.f, 0.f, 0.f, 0.f};

  const float* xrow = &x[(long long)arow * D_IN];

#pragma unroll
  for (int kstep = 0; kstep < 8; ++kstep) {
    const int kbase = kstep * 32 + quad * 8;
    float4 a0 = *(const float4*)&xrow[kbase];
    float4 a1 = *(const float4*)&xrow[kbase + 4];
    short8 af;
    af[0] = (short)f2bf(a0.x); af[1] = (short)f2bf(a0.y);
    af[2] = (short)f2bf(a0.z); af[3] = (short)f2bf(a0.w);
    af[4] = (short)f2bf(a1.x); af[5] = (short)f2bf(a1.y);
    af[6] = (short)f2bf(a1.z); af[7] = (short)f2bf(a1.w);
#pragma unroll
    for (int nt = 0; nt < 4; ++nt) {
      uint4 bu = gswz[(nt * 8 + kstep) * 64 + lane];
      short8 bf = *(short8*)&bu;
      acc[nt] = __builtin_amdgcn_mfma_f32_16x16x32_bf16(af, bf, acc[nt], 0, 0, 0);
    }
  }

#pragma unroll
  for (int nt = 0; nt < 4; ++nt) {
#pragma unroll
    for (int r = 0; r < 4; ++r) {
      int orow = rowbase + quad * 4 + r;
      if (orow < M)
        h1[(long long)orow * D_HID + nt * 16 + m] = f2bf(acc[nt][r]);
    }
  }
}

// ---------------------------------------------------------------------------
// Team-vectorized CSR SPMM: TEAM = D/4 lanes per row, uint2 (4 bf16) per lane.
// R12: 8-edge unrolled main loop -> 8 independent row-gathers in flight.
template <int D, bool RELU>
__global__ __launch_bounds__(256) void spmm_csr_kernel(
    const int* __restrict__ rs, const u32* __restrict__ csr,
    const u16* __restrict__ in, const float* __restrict__ bias,
    u16* __restrict__ out, int M) {
  constexpr int TEAM = D / 4;
  constexpr int SH = (D == 64) ? 6 : 5;   // u16 elems per row = D = 1<<SH
  const int lt = threadIdx.x % TEAM;
  const int row = blockIdx.x * (256 / TEAM) + threadIdx.x / TEAM;
  if (row >= M) return;
  const int start = (row == 0) ? 0 : rs[row - 1];
  const int end = rs[row];
  const float qs = 1.f / 32768.f;
  const u16* inp = in + lt * 4;

  float a0 = 0.f, a1 = 0.f, a2 = 0.f, a3 = 0.f;
  int j = start;

  // head peel to 16B-aligned csr index
  int head = (4 - (start & 3)) & 3;
  if (head > end - start) head = end - start;
  for (int h = 0; h < head; ++h, ++j) {
    u32 pk = csr[j];
    uint2 w = *(const uint2*)(inp + ((pk >> 15) << SH));
    float v = (float)(pk & 32767u) * qs;
    a0 = fmaf(v, bf2f(w.x), a0); a1 = fmaf(v, bf2f_hi(w.x), a1);
    a2 = fmaf(v, bf2f(w.y), a2); a3 = fmaf(v, bf2f_hi(w.y), a3);
  }

  // 8-edge main loop: 2 independent csr uint4 + 8 gathers issued before FMAs
  for (; j + 8 <= end; j += 8) {
    uint4 pa = *(const uint4*)&csr[j];
    uint4 pb = *(const uint4*)&csr[j + 4];
    uint2 w0 = *(const uint2*)(inp + ((pa.x >> 15) << SH));
    uint2 w1 = *(const uint2*)(inp + ((pa.y >> 15) << SH));
    uint2 w2 = *(const uint2*)(inp + ((pa.z >> 15) << SH));
    uint2 w3 = *(const uint2*)(inp + ((pa.w >> 15) << SH));
    uint2 w4 = *(const uint2*)(inp + ((pb.x >> 15) << SH));
    uint2 w5 = *(const uint2*)(inp + ((pb.y >> 15) << SH));
    uint2 w6 = *(const uint2*)(inp + ((pb.z >> 15) << SH));
    uint2 w7 = *(const uint2*)(inp + ((pb.w >> 15) << SH));
    float v0 = (float)(pa.x & 32767u) * qs;
    float v1 = (float)(pa.y & 32767u) * qs;
    float v2 = (float)(pa.z & 32767u) * qs;
    float v3 = (float)(pa.w & 32767u) * qs;
    float v4 = (float)(pb.x & 32767u) * qs;
    float v5 = (float)(pb.y & 32767u) * qs;
    float v6 = (float)(pb.z & 32767u) * qs;
    float v7 = (float)(pb.w & 32767u) * qs;
    a0 = fmaf(v0, bf2f(w0.x), a0); a1 = fmaf(v0, bf2f_hi(w0.x), a1);
    a2 = fmaf(v0, bf2f(w0.y), a2); a3 = fmaf(v0, bf2f_hi(w0.y), a3);
    a0 = fmaf(v1, bf2f(w1.x), a0); a1 = fmaf(v1, bf2f_hi(w1.x), a1);
    a2 = fmaf(v1, bf2f(w1.y), a2); a3 = fmaf(v1, bf2f_hi(w1.y), a3);
    a0 = fmaf(v2, bf2f(w2.x), a0); a1 = fmaf(v2, bf2f_hi(w2.x), a1);
    a2 = fmaf(v2, bf2f(w2.y), a2); a3 = fmaf(v2, bf2f_hi(w2.y), a3);
    a0 = fmaf(v3, bf2f(w3.x), a0); a1 = fmaf(v3, bf2f_hi(w3.x), a1);
    a2 = fmaf(v3, bf2f(w3.y), a2); a3 = fmaf(v3, bf2f_hi(w3.y), a3);
    a0 = fmaf(v4, bf2f(w4.x), a0); a1 = fmaf(v4, bf2f_hi(w4.x), a1);
    a2 = fmaf(v4, bf2f(w4.y), a2); a3 = fmaf(v4, bf2f_hi(w4.y), a3);
    a0 = fmaf(v5, bf2f(w5.x), a0); a1 = fmaf(v5, bf2f_hi(w5.x), a1);
    a2 = fmaf(v5, bf2f(w5.y), a2); a3 = fmaf(v5, bf2f_hi(w5.y), a3);
    a0 = fmaf(v6, bf2f(w6.x), a0); a1 = fmaf(v6, bf2f_hi(w6.x), a1);
    a2 = fmaf(v6, bf2f(w6.y), a2); a3 = fmaf(v6, bf2f_hi(w6.y), a3);
    a0 = fmaf(v7, bf2f(w7.x), a0); a1 = fmaf(v7, bf2f_hi(w7.x), a1);
    a2 = fmaf(v7, bf2f(w7.y), a2); a3 = fmaf(v7, bf2f_hi(w7.y), a3);
  }

  for (; j + 4 <= end; j += 4) {
    uint4 p = *(const uint4*)&csr[j];
    uint2 w0 = *(const uint2*)(inp + ((p.x >> 15) << SH));
    uint2 w1 = *(const uint2*)(inp + ((p.y >> 15) << SH));
    uint2 w2 = *(const uint2*)(inp + ((p.z >> 15) << SH));
    uint2 w3 = *(const uint2*)(inp + ((p.w >> 15) << SH));
    float v0 = (float)(p.x & 32767u) * qs;
    float v1 = (float)(p.y & 32767u) * qs;
    float v2 = (float)(p.z & 32767u) * qs;
    float v3 = (float)(p.w & 32767u) * qs;
    a0 = fmaf(v0, bf2f(w0.x), a0); a1 = fmaf(v0, bf2f_hi(w0.x), a1);
    a2 = fmaf(v0, bf2f(w0.y), a2); a3 = fmaf(v0, bf2f_hi(w0.y), a3);
    a0 = fmaf(v1, bf2f(w1.x), a0); a1 = fmaf(v1, bf2f_hi(w1.x), a1);
    a2 = fmaf(v1, bf2f(w1.y), a2); a3 = fmaf(v1, bf2f_hi(w1.y), a3);
    a0 = fmaf(v2, bf2f(w2.x), a0); a1 = fmaf(v2, bf2f_hi(w2.x), a1);
    a2 = fmaf(v2, bf2f(w2.y), a2); a3 = fmaf(v2, bf2f_hi(w2.y), a3);
    a0 = fmaf(v3, bf2f(w3.x), a0); a1 = fmaf(v3, bf2f_hi(w3.x), a1);
    a2 = fmaf(v3, bf2f(w3.y), a2); a3 = fmaf(v3, bf2f_hi(w3.y), a3);
  }
  for (; j < end; ++j) {
    u32 pk = csr[j];
    uint2 w = *(const uint2*)(inp + ((pk >> 15) << SH));
    float v = (float)(pk & 32767u) * qs;
    a0 = fmaf(v, bf2f(w.x), a0); a1 = fmaf(v, bf2f_hi(w.x), a1);
    a2 = fmaf(v, bf2f(w.y), a2); a3 = fmaf(v, bf2f_hi(w.y), a3);
  }
  const float4 bv = *(const float4*)&bias[lt * 4];
  a0 += bv.x; a1 += bv.y; a2 += bv.z; a3 += bv.w;
  if (RELU) {
    a0 = fmaxf(a0, 0.f); a1 = fmaxf(a1, 0.f);
    a2 = fmaxf(a2, 0.f); a3 = fmaxf(a3, 0.f);
  }
  uint2 o;
  o.x = (u32)f2bf(a0) | ((u32)f2bf(a1) << 16);
  o.y = (u32)f2bf(a2) | ((u32)f2bf(a3) << 16);
  *(uint2*)&out[((u32)row << SH) + lt * 4] = o;
}

// ---------------------------------------------------------------------------
// GEMM2: h2[M,32](bf16) = z1[M,64](bf16) @ W2[64,32](f32)
__global__ __launch_bounds__(256) void gemm2_kernel(
    const u16* __restrict__ z1, const float* __restrict__ W2,
    u16* __restrict__ h2, int M) {
  __shared__ float wsm[D_HID * D_EMB];
  const int tid = threadIdx.x;
  for (int i = tid; i < D_HID * D_EMB / 4; i += 256)
    ((float4*)wsm)[i] = ((const float4*)W2)[i];
  __syncthreads();

  const int row = blockIdx.x * 256 + tid;
  if (row >= M) return;

  float4 acc4[8];
  for (int c = 0; c < 8; ++c) acc4[c] = make_float4(0.f, 0.f, 0.f, 0.f);

  const uint4* zr = (const uint4*)&z1[(long long)row * D_HID];
  for (int blk = 0; blk < 8; ++blk) {
    float a8[8];
    unpack8(zr[blk], a8);
    for (int kk = 0; kk < 8; ++kk) {
      const float a = a8[kk];
      const float4* wr = (const float4*)&wsm[(blk * 8 + kk) * D_EMB];
      for (int c = 0; c < 8; ++c) {
        float4 wv = wr[c];
        acc4[c].x += a * wv.x;
        acc4[c].y += a * wv.y;
        acc4[c].z += a * wv.z;
        acc4[c].w += a * wv.w;
      }
    }
  }
  u32 pk[16];
  for (int c = 0; c < 8; ++c) {
    pk[c * 2 + 0] = (u32)f2bf(acc4[c].x) | ((u32)f2bf(acc4[c].y) << 16);
    pk[c * 2 + 1] = (u32)f2bf(acc4[c].z) | ((u32)f2bf(acc4[c].w) << 16);
  }
  uint4* op = (uint4*)&h2[(long long)row * D_EMB];
  op[0] = make_uint4(pk[0], pk[1], pk[2], pk[3]);
  op[1] = make_uint4(pk[4], pk[5], pk[6], pk[7]);
  op[2] = make_uint4(pk[8], pk[9], pk[10], pk[11]);
  op[3] = make_uint4(pk[12], pk[13], pk[14], pk[15]);
}

// ---------------------------------------------------------------------------
// Decoder: scores[e] = dot(z2[src], z2[dst]). R12: 2 edges per thread,
// all 8 uint4 gathers issued before the dot-product chains.
__global__ __launch_bounds__(256) void decode_kernel(
    const int* __restrict__ ei, const u16* __restrict__ z2,
    float* __restrict__ out, int nE) {
  const int t = blockIdx.x * 256 + threadIdx.x;
  const int e0 = t * 2;
  if (e0 >= nE) return;
  const bool two = (e0 + 1 < nE);

  const int2 ss = *(const int2*)&ei[e0];
  const int2 dd = *(const int2*)&ei[nE + e0];

  const uint4* za = (const uint4*)(z2 + ((u32)ss.x << 5));
  const uint4* zb = (const uint4*)(z2 + ((u32)dd.x << 5));
  const uint4* zc = (const uint4*)(z2 + ((u32)(two ? ss.y : ss.x) << 5));
  const uint4* zd = (const uint4*)(z2 + ((u32)(two ? dd.y : dd.x) << 5));

  uint4 A[2], B[2], C[2], Dv[2];
  A[0] = za[0]; A[1] = za[1];
  B[0] = zb[0]; B[1] = zb[1];
  C[0] = zc[0]; C[1] = zc[1];
  Dv[0] = zd[0]; Dv[1] = zd[1];
  uint4 A2[2], B2[2], C2[2], D2[2];
  A2[0] = za[2]; A2[1] = za[3];
  B2[0] = zb[2]; B2[1] = zb[3];
  C2[0] = zc[2]; C2[1] = zc[3];
  D2[0] = zd[2]; D2[1] = zd[3];

  float acc0 = 0.f, acc1 = 0.f;
  float a8[8], b8[8];
#pragma unroll
  for (int c = 0; c < 2; ++c) {
    unpack8(A[c], a8); unpack8(B[c], b8);
#pragma unroll
    for (int k = 0; k < 8; ++k) acc0 = fmaf(a8[k], b8[k], acc0);
    unpack8(A2[c], a8); unpack8(B2[c], b8);
#pragma unroll
    for (int k = 0; k < 8; ++k) acc0 = fmaf(a8[k], b8[k], acc0);
    unpack8(C[c], a8); unpack8(Dv[c], b8);
#pragma unroll
    for (int k = 0; k < 8; ++k) acc1 = fmaf(a8[k], b8[k], acc1);
    unpack8(C2[c], a8); unpack8(D2[c], b8);
#pragma unroll
    for (int k = 0; k < 8; ++k) acc1 = fmaf(a8[k], b8[k], acc1);
  }
  out[e0] = acc0;
  if (two) out[e0 + 1] = acc1;
}

// ---------------------------------------------------------------------------
extern "C" void kernel_launch(void* const* d_in, const int* in_sizes, int n_in,
                              void* d_out, int out_size, void* d_ws, size_t ws_size,
                              hipStream_t stream) {
  const float* x       = (const float*)d_in[0];
  const int*   adj_src = (const int*)d_in[1];
  const int*   adj_dst = (const int*)d_in[2];
  const float* adj_val = (const float*)d_in[3];
  const int*   ei      = (const int*)d_in[4];
  const float* W1      = (const float*)d_in[5];
  const float* b1      = (const float*)d_in[6];
  const float* W2      = (const float*)d_in[7];
  const float* b2      = (const float*)d_in[8];

  const int M   = in_sizes[0] / D_IN;      // 100000
  const int nnz = in_sizes[1];             // 3200000
  const int nE  = in_sizes[4] / 2;         // 2000000

  const int NBUK = (M + BROWS - 1) / BROWS;  // 391

  // Workspace (76.8 MB):
  //   [0, 12.8):     csr packed u32
  //   [12.8, 38.4):  payload int2 (dead after sort) -> h1 bf16, h2 reuse
  //   [38.4, 51.2):  z1 bf16, z2 reuse
  //   [60.0, +32KB): gswz (pre-swizzled W1 bf16 fragments)
  char* ws = (char*)d_ws;
  u32*   csr     = (u32*)(ws);
  int2*  payload = (int2*)(ws + (size_t)nnz * 4);
  u16*   h1      = (u16*)(ws + (size_t)nnz * 4);
  u16*   z1      = (u16*)(ws + (size_t)nnz * 4 + (size_t)nnz * 8);
  u16*   h2      = h1;
  u16*   z2      = z1;
  uint4* gswz    = (uint4*)(ws + 60ull * 1024 * 1024);

  // Small scratch in d_out (8 MB, dead until decode):
  int* rs    = (int*)d_out;                 // M ints
  int* bscan = (int*)d_out + 112 * 1024;    // NBUK+1 ints
  int* cur   = (int*)d_out + 120 * 1024;    // NBUK ints

  // --- W1 swizzle ---
  w1_swizzle_kernel<<<8, 256, 0, stream>>>(W1, gswz);

  // --- bucket partition ---
  hipMemsetAsync(bscan, 0, (size_t)(NBUK + 1) * 4, stream);
  bin_count<<<256, 256, 0, stream>>>(adj_dst, bscan, nnz, NBUK);
  bin_scan<<<1, 256, 0, stream>>>(bscan, cur, NBUK);
  partition_kernel<<<(nnz + TILE - 1) / TILE, PBS, 0, stream>>>(
      adj_src, adj_dst, adj_val, cur, payload, nnz, NBUK);

  // --- bucket-local counting sort -> packed CSR + rs ---
  bucket_sort_kernel<<<NBUK, SBS, 0, stream>>>(bscan, payload, csr, rs, M);

  // --- GEMM1 via MFMA ---
  gemm1_mfma_kernel<<<(M + 63) / 64, 256, 0, stream>>>(x, gswz, h1, M);

  // --- SPMM1 + b1 + ReLU (16-lane teams) ---
  spmm_csr_kernel<D_HID, true><<<(M + 15) / 16, 256, 0, stream>>>(
      rs, csr, h1, b1, z1, M);

  // --- GEMM2 ---
  gemm2_kernel<<<(M + 255) / 256, 256, 0, stream>>>(z1, W2, h2, M);

  // --- SPMM2 + b2 (8-lane teams) ---
  spmm_csr_kernel<D_EMB, false><<<(M + 31) / 32, 256, 0, stream>>>(
      rs, csr, h2, b2, z2, M);

  // --- Decode (2 edges/thread, overwrites d_out scratch) ---
  decode_kernel<<<(nE / 2 + 255) / 256, 256, 0, stream>>>(ei, z2, (float*)d_out, nE);
}

// Round 4
// 417.468 us; speedup vs baseline: 1.6895x; 1.0386x over previous
//
#include <hip/hip_runtime.h>
#include <hip/hip_bf16.h>

// GCN link predictor, Round 13: fuse GEMM2 into SPMM1's epilogue.
// R12 postmortem: 8-edge MLP unroll gained only ~4us -> SPMM gather loop is
// at its structural service rate (h1 12.8MB > 4MB/XCD L2, L3-backed).
// Remaining levers are structural: gemm2 is a pure epilogue of spmm1 (each
// 16-lane team ends holding the full 64-dim z1 row in regs). R13 stages z1
// through a padded LDS tile (68-float skew, conflict-free) + W2 in 8KB LDS;
// each lane computes 2 cols of h2 = z1@W2 and stores the 64B h2 row
// coalesced. Deletes the gemm2 dispatch + 25.6MB z1 round-trip; z1 now
// feeds gemm2 unrounded f32. Sort pipeline / gemm1 / spmm2 / decode
// unchanged from R12.

#define D_IN  256
#define D_HID 64
#define D_EMB 32
#define BROWS 256       // dst-rows per bucket
#define NBUK_MAX 512    // >= ceil(M/BROWS) = 391
#define TILE  4096      // edges per partition tile
#define PBS   512       // partition block size (PER = 8)
#define SBS   1024      // bucket_sort block size

typedef unsigned short u16;
typedef unsigned int u32;
typedef __attribute__((ext_vector_type(8))) short short8;   // 8 bf16
typedef __attribute__((ext_vector_type(4))) float f32x4;

__device__ __forceinline__ float bf2f(u32 u) {
  return __uint_as_float((u & 0xFFFFu) << 16);
}
__device__ __forceinline__ float bf2f_hi(u32 u) {
  return __uint_as_float(u & 0xFFFF0000u);
}
__device__ __forceinline__ u16 f2bf(float f) {
  u32 x = __float_as_uint(f);
  x += 0x7FFFu + ((x >> 16) & 1u);  // RNE
  return (u16)(x >> 16);
}
__device__ __forceinline__ void unpack8(uint4 u, float* f) {
  f[0] = bf2f(u.x); f[1] = bf2f(u.x >> 16);
  f[2] = bf2f(u.y); f[3] = bf2f(u.y >> 16);
  f[4] = bf2f(u.z); f[5] = bf2f(u.z >> 16);
  f[6] = bf2f(u.w); f[7] = bf2f(u.w >> 16);
}

// ---------------------------------------------------------------------------
// One-time W1 swizzle: fp32 [256,64] -> bf16 B-fragments.
__global__ __launch_bounds__(256) void w1_swizzle_kernel(
    const float* __restrict__ W1, uint4* __restrict__ gswz) {
  const int s = blockIdx.x * 256 + threadIdx.x;  // 2048 slots
  const int lane = s & 63;
  const int kstep = (s >> 6) & 7;
  const int nt = s >> 9;
  const int col = nt * 16 + (lane & 15);
  const int kbase = kstep * 32 + (lane >> 4) * 8;
  u32 p[4];
  for (int jp = 0; jp < 4; ++jp) {
    u32 lo = f2bf(W1[(kbase + 2 * jp) * D_HID + col]);
    u32 hi = f2bf(W1[(kbase + 2 * jp + 1) * D_HID + col]);
    p[jp] = lo | (hi << 16);
  }
  gswz[s] = make_uint4(p[0], p[1], p[2], p[3]);
}

// ---------------------------------------------------------------------------
// Bucket histogram (LDS-staged).
__global__ __launch_bounds__(256) void bin_count(
    const int* __restrict__ dst, int* __restrict__ hist, int nnz, int nbuk) {
  __shared__ int h[NBUK_MAX];
  for (int i = threadIdx.x; i < nbuk; i += 256) h[i] = 0;
  __syncthreads();
  const int stride = gridDim.x * 256;
  for (int e = blockIdx.x * 256 + threadIdx.x; e < nnz; e += stride)
    atomicAdd(&h[dst[e] >> 8], 1);
  __syncthreads();
  for (int i = threadIdx.x; i < nbuk; i += 256) {
    int v = h[i];
    if (v) atomicAdd(&hist[i], v);
  }
}

// 1-block exclusive scan (in place), copy to cur, sentinel hist[n] = total.
__global__ __launch_bounds__(256) void bin_scan(
    int* __restrict__ hist, int* __restrict__ cur, int n) {
  __shared__ int sm[256];
  const int t = threadIdx.x;
  const int per = (n + 255) / 256;
  const int base = t * per;
  int loc[4];
  int s = 0;
  for (int i = 0; i < per; ++i) {
    int idx = base + i;
    int v = (idx < n) ? hist[idx] : 0;
    loc[i] = s;
    s += v;
  }
  sm[t] = s;
  __syncthreads();
  for (int off = 1; off < 256; off <<= 1) {
    int tmp = (t >= off) ? sm[t - off] : 0;
    __syncthreads();
    sm[t] += tmp;
    __syncthreads();
  }
  const int b0 = sm[t] - s;
  for (int i = 0; i < per; ++i) {
    int idx = base + i;
    if (idx < n) {
      int p = b0 + loc[i];
      hist[idx] = p;
      cur[idx] = p;
    }
  }
  if (t == 255) hist[n] = sm[255];
}

// ---------------------------------------------------------------------------
// Tile-staged partition, 512 threads, 40KB LDS => 4 blocks/CU (32 waves).
// payload: .x = src<<8 | dstlow, .y = bucket<<15 | q15(val).
__global__ __launch_bounds__(PBS) void partition_kernel(
    const int* __restrict__ src, const int* __restrict__ dst,
    const float* __restrict__ val, int* __restrict__ cur,
    int2* __restrict__ payload, int nnz, int nbuk) {
  __shared__ int2 stage[TILE];            // 32 KB
  __shared__ int hist[NBUK_MAX];          // 2 KB: counts -> local excl offsets
  __shared__ int lcur[NBUK_MAX];          // 2 KB
  __shared__ int gbase[NBUK_MAX];         // 2 KB
  __shared__ int sm[PBS];                 // 2 KB

  const int t = threadIdx.x;
  const long long base = (long long)blockIdx.x * TILE;
  const int cnt = min(TILE, (int)(nnz - base));

  for (int i = t; i < nbuk; i += PBS) hist[i] = 0;
  __syncthreads();

  constexpr int PER = TILE / PBS;  // 8
  int key[PER], vq[PER];
  short bk[PER];
  for (int i = 0; i < PER; ++i) {
    int idx = t + i * PBS;
    if (idx < cnt) {
      int d = dst[base + idx];
      int b = d >> 8;
      bk[i] = (short)b;
      key[i] = (src[base + idx] << 8) | (d & (BROWS - 1));
      int q = (int)(val[base + idx] * 32768.f + 0.5f);
      q = min(q, 32767);
      vq[i] = (b << 15) | q;
      atomicAdd(&hist[b], 1);
    } else {
      bk[i] = -1;
    }
  }
  __syncthreads();

  // scan hist (nbuk <= PBS) -> exclusive offsets; reserve global chunks
  {
    int c = (t < nbuk) ? hist[t] : 0;
    sm[t] = c;
    __syncthreads();
    for (int off = 1; off < PBS; off <<= 1) {
      int tmp = (t >= off) ? sm[t - off] : 0;
      __syncthreads();
      sm[t] += tmp;
      __syncthreads();
    }
    int excl = sm[t] - c;
    if (t < nbuk) {
      hist[t] = excl;
      lcur[t] = excl;
      if (c > 0) gbase[t] = atomicAdd(&cur[t], c);
    }
  }
  __syncthreads();

  // counting sort into stage
  for (int i = 0; i < PER; ++i) {
    if (bk[i] >= 0) {
      int p = atomicAdd(&lcur[bk[i]], 1);
      stage[p] = make_int2(key[i], vq[i]);
    }
  }
  __syncthreads();

  // contiguous run write-out (bucket recovered from .y)
  for (int i = t; i < cnt; i += PBS) {
    int2 pk = stage[i];
    int b = pk.y >> 15;
    payload[gbase[b] + (i - hist[b])] = pk;
  }
}

// ---------------------------------------------------------------------------
// Bucket-local counting sort -> 4B packed CSR (src:17 | q15) + inclusive rs.
// 1024 threads/block; scan by first 256 lanes.
__global__ __launch_bounds__(SBS) void bucket_sort_kernel(
    const int* __restrict__ bscan, const int2* __restrict__ payload,
    u32* __restrict__ csr, int* __restrict__ rs, int M) {
  __shared__ int cnt_s[BROWS];
  __shared__ int sm[BROWS];
  const int b = blockIdx.x;
  const int t = threadIdx.x;
  const int start = bscan[b];
  const int end = bscan[b + 1];

  if (t < BROWS) cnt_s[t] = 0;
  __syncthreads();
  for (int j = start + t; j < end; j += SBS)
    atomicAdd(&cnt_s[payload[j].x & (BROWS - 1)], 1);
  __syncthreads();

  int v = 0;
  if (t < BROWS) { v = cnt_s[t]; sm[t] = v; }
  __syncthreads();
  for (int off = 1; off < BROWS; off <<= 1) {
    int tmp = 0;
    if (t < BROWS && t >= off) tmp = sm[t - off];
    __syncthreads();
    if (t < BROWS) sm[t] += tmp;
    __syncthreads();
  }
  if (t < BROWS) {
    int row = b * BROWS + t;
    if (row < M) rs[row] = start + sm[t];    // inclusive row end
    cnt_s[t] = start + sm[t] - v;            // exclusive cursor
  }
  __syncthreads();

  for (int j = start + t; j < end; j += SBS) {
    int2 pk = payload[j];
    int r = pk.x & (BROWS - 1);
    int p = atomicAdd(&cnt_s[r], 1);
    csr[p] = ((u32)(pk.x >> 8) << 15) | (u32)(pk.y & 32767);
  }
}

// ---------------------------------------------------------------------------
// GEMM1 via MFMA: h1[M,64](bf16) = x[M,256](f32 -> bf16) @ W1.
__global__ __launch_bounds__(256) void gemm1_mfma_kernel(
    const float* __restrict__ x, const uint4* __restrict__ gswz,
    u16* __restrict__ h1, int M) {
  const int tid = threadIdx.x;
  const int wv = tid >> 6;
  const int lane = tid & 63;
  const int quad = lane >> 4;
  const int m = lane & 15;

  const int rowbase = blockIdx.x * 64 + wv * 16;
  int arow = rowbase + m;
  if (arow >= M) arow = M - 1;

  f32x4 acc[4];
  for (int nt = 0; nt < 4; ++nt) acc[nt] = (f32x4){0.f, 0.f, 0.f, 0.f};

  const float* xrow = &x[(long long)arow * D_IN];

#pragma unroll
  for (int kstep = 0; kstep < 8; ++kstep) {
    const int kbase = kstep * 32 + quad * 8;
    float4 a0 = *(const float4*)&xrow[kbase];
    float4 a1 = *(const float4*)&xrow[kbase + 4];
    short8 af;
    af[0] = (short)f2bf(a0.x); af[1] = (short)f2bf(a0.y);
    af[2] = (short)f2bf(a0.z); af[3] = (short)f2bf(a0.w);
    af[4] = (short)f2bf(a1.x); af[5] = (short)f2bf(a1.y);
    af[6] = (short)f2bf(a1.z); af[7] = (short)f2bf(a1.w);
#pragma unroll
    for (int nt = 0; nt < 4; ++nt) {
      uint4 bu = gswz[(nt * 8 + kstep) * 64 + lane];
      short8 bf = *(short8*)&bu;
      acc[nt] = __builtin_amdgcn_mfma_f32_16x16x32_bf16(af, bf, acc[nt], 0, 0, 0);
    }
  }

#pragma unroll
  for (int nt = 0; nt < 4; ++nt) {
#pragma unroll
    for (int r = 0; r < 4; ++r) {
      int orow = rowbase + quad * 4 + r;
      if (orow < M)
        h1[(long long)orow * D_HID + nt * 16 + m] = f2bf(acc[nt][r]);
    }
  }
}

// ---------------------------------------------------------------------------
// SPMM1 + b1 + ReLU fused with GEMM2: h2[M,32] = relu(A@h1 + b1) @ W2.
// 16-lane teams; z1 row staged in padded LDS (68-float skew, conflict-free
// broadcast); W2 in 8KB LDS. Within-wave LDS producer->consumer (no barrier).
__global__ __launch_bounds__(256) void spmm1_gemm2_fused(
    const int* __restrict__ rs, const u32* __restrict__ csr,
    const u16* __restrict__ in, const float* __restrict__ b1,
    const float* __restrict__ W2, u16* __restrict__ h2, int M) {
  __shared__ float w2s[D_HID * D_EMB];   // 8 KB
  __shared__ float z1s[16][68];          // 4.25 KB, +4 skew per team row

  const int tid = threadIdx.x;
  for (int i = tid; i < D_HID * D_EMB / 4; i += 256)
    ((float4*)w2s)[i] = ((const float4*)W2)[i];
  __syncthreads();

  const int lt = tid & 15;
  const int tb = tid >> 4;                    // team in block (0..15)
  const int row = blockIdx.x * 16 + tb;
  if (row >= M) return;

  const int start = (row == 0) ? 0 : rs[row - 1];
  const int end = rs[row];
  const float qs = 1.f / 32768.f;
  const u16* inp = in + lt * 4;

  float a0 = 0.f, a1 = 0.f, a2 = 0.f, a3 = 0.f;
  int j = start;

  // head peel to 16B-aligned csr index
  int head = (4 - (start & 3)) & 3;
  if (head > end - start) head = end - start;
  for (int h = 0; h < head; ++h, ++j) {
    u32 pk = csr[j];
    uint2 w = *(const uint2*)(inp + ((pk >> 15) << 6));
    float v = (float)(pk & 32767u) * qs;
    a0 = fmaf(v, bf2f(w.x), a0); a1 = fmaf(v, bf2f_hi(w.x), a1);
    a2 = fmaf(v, bf2f(w.y), a2); a3 = fmaf(v, bf2f_hi(w.y), a3);
  }

  // 8-edge main loop: 2 independent csr uint4 + 8 gathers in flight
  for (; j + 8 <= end; j += 8) {
    uint4 pa = *(const uint4*)&csr[j];
    uint4 pb = *(const uint4*)&csr[j + 4];
    uint2 w0 = *(const uint2*)(inp + ((pa.x >> 15) << 6));
    uint2 w1 = *(const uint2*)(inp + ((pa.y >> 15) << 6));
    uint2 w2 = *(const uint2*)(inp + ((pa.z >> 15) << 6));
    uint2 w3 = *(const uint2*)(inp + ((pa.w >> 15) << 6));
    uint2 w4 = *(const uint2*)(inp + ((pb.x >> 15) << 6));
    uint2 w5 = *(const uint2*)(inp + ((pb.y >> 15) << 6));
    uint2 w6 = *(const uint2*)(inp + ((pb.z >> 15) << 6));
    uint2 w7 = *(const uint2*)(inp + ((pb.w >> 15) << 6));
    float v0 = (float)(pa.x & 32767u) * qs;
    float v1 = (float)(pa.y & 32767u) * qs;
    float v2 = (float)(pa.z & 32767u) * qs;
    float v3 = (float)(pa.w & 32767u) * qs;
    float v4 = (float)(pb.x & 32767u) * qs;
    float v5 = (float)(pb.y & 32767u) * qs;
    float v6 = (float)(pb.z & 32767u) * qs;
    float v7 = (float)(pb.w & 32767u) * qs;
    a0 = fmaf(v0, bf2f(w0.x), a0); a1 = fmaf(v0, bf2f_hi(w0.x), a1);
    a2 = fmaf(v0, bf2f(w0.y), a2); a3 = fmaf(v0, bf2f_hi(w0.y), a3);
    a0 = fmaf(v1, bf2f(w1.x), a0); a1 = fmaf(v1, bf2f_hi(w1.x), a1);
    a2 = fmaf(v1, bf2f(w1.y), a2); a3 = fmaf(v1, bf2f_hi(w1.y), a3);
    a0 = fmaf(v2, bf2f(w2.x), a0); a1 = fmaf(v2, bf2f_hi(w2.x), a1);
    a2 = fmaf(v2, bf2f(w2.y), a2); a3 = fmaf(v2, bf2f_hi(w2.y), a3);
    a0 = fmaf(v3, bf2f(w3.x), a0); a1 = fmaf(v3, bf2f_hi(w3.x), a1);
    a2 = fmaf(v3, bf2f(w3.y), a2); a3 = fmaf(v3, bf2f_hi(w3.y), a3);
    a0 = fmaf(v4, bf2f(w4.x), a0); a1 = fmaf(v4, bf2f_hi(w4.x), a1);
    a2 = fmaf(v4, bf2f(w4.y), a2); a3 = fmaf(v4, bf2f_hi(w4.y), a3);
    a0 = fmaf(v5, bf2f(w5.x), a0); a1 = fmaf(v5, bf2f_hi(w5.x), a1);
    a2 = fmaf(v5, bf2f(w5.y), a2); a3 = fmaf(v5, bf2f_hi(w5.y), a3);
    a0 = fmaf(v6, bf2f(w6.x), a0); a1 = fmaf(v6, bf2f_hi(w6.x), a1);
    a2 = fmaf(v6, bf2f(w6.y), a2); a3 = fmaf(v6, bf2f_hi(w6.y), a3);
    a0 = fmaf(v7, bf2f(w7.x), a0); a1 = fmaf(v7, bf2f_hi(w7.x), a1);
    a2 = fmaf(v7, bf2f(w7.y), a2); a3 = fmaf(v7, bf2f_hi(w7.y), a3);
  }

  for (; j + 4 <= end; j += 4) {
    uint4 p = *(const uint4*)&csr[j];
    uint2 w0 = *(const uint2*)(inp + ((p.x >> 15) << 6));
    uint2 w1 = *(const uint2*)(inp + ((p.y >> 15) << 6));
    uint2 w2 = *(const uint2*)(inp + ((p.z >> 15) << 6));
    uint2 w3 = *(const uint2*)(inp + ((p.w >> 15) << 6));
    float v0 = (float)(p.x & 32767u) * qs;
    float v1 = (float)(p.y & 32767u) * qs;
    float v2 = (float)(p.z & 32767u) * qs;
    float v3 = (float)(p.w & 32767u) * qs;
    a0 = fmaf(v0, bf2f(w0.x), a0); a1 = fmaf(v0, bf2f_hi(w0.x), a1);
    a2 = fmaf(v0, bf2f(w0.y), a2); a3 = fmaf(v0, bf2f_hi(w0.y), a3);
    a0 = fmaf(v1, bf2f(w1.x), a0); a1 = fmaf(v1, bf2f_hi(w1.x), a1);
    a2 = fmaf(v1, bf2f(w1.y), a2); a3 = fmaf(v1, bf2f_hi(w1.y), a3);
    a0 = fmaf(v2, bf2f(w2.x), a0); a1 = fmaf(v2, bf2f_hi(w2.x), a1);
    a2 = fmaf(v2, bf2f(w2.y), a2); a3 = fmaf(v2, bf2f_hi(w2.y), a3);
    a0 = fmaf(v3, bf2f(w3.x), a0); a1 = fmaf(v3, bf2f_hi(w3.x), a1);
    a2 = fmaf(v3, bf2f(w3.y), a2); a3 = fmaf(v3, bf2f_hi(w3.y), a3);
  }
  for (; j < end; ++j) {
    u32 pk = csr[j];
    uint2 w = *(const uint2*)(inp + ((pk >> 15) << 6));
    float v = (float)(pk & 32767u) * qs;
    a0 = fmaf(v, bf2f(w.x), a0); a1 = fmaf(v, bf2f_hi(w.x), a1);
    a2 = fmaf(v, bf2f(w.y), a2); a3 = fmaf(v, bf2f_hi(w.y), a3);
  }

  const float4 bv = *(const float4*)&b1[lt * 4];
  a0 = fmaxf(a0 + bv.x, 0.f);
  a1 = fmaxf(a1 + bv.y, 0.f);
  a2 = fmaxf(a2 + bv.z, 0.f);
  a3 = fmaxf(a3 + bv.w, 0.f);

  // --- fused GEMM2 epilogue: h2[row] = z1row @ W2 ---
  float* zrow = z1s[tb];
  zrow[lt * 4 + 0] = a0;
  zrow[lt * 4 + 1] = a1;
  zrow[lt * 4 + 2] = a2;
  zrow[lt * 4 + 3] = a3;
  // same wave: LDS ops in order, no barrier needed
  float h0 = 0.f, h1v = 0.f;
#pragma unroll
  for (int k = 0; k < D_HID; k += 4) {
    float4 z4 = *(const float4*)&zrow[k];
    h0  = fmaf(z4.x, w2s[(k + 0) * D_EMB + 2 * lt], h0);
    h1v = fmaf(z4.x, w2s[(k + 0) * D_EMB + 2 * lt + 1], h1v);
    h0  = fmaf(z4.y, w2s[(k + 1) * D_EMB + 2 * lt], h0);
    h1v = fmaf(z4.y, w2s[(k + 1) * D_EMB + 2 * lt + 1], h1v);
    h0  = fmaf(z4.z, w2s[(k + 2) * D_EMB + 2 * lt], h0);
    h1v = fmaf(z4.z, w2s[(k + 2) * D_EMB + 2 * lt + 1], h1v);
    h0  = fmaf(z4.w, w2s[(k + 3) * D_EMB + 2 * lt], h0);
    h1v = fmaf(z4.w, w2s[(k + 3) * D_EMB + 2 * lt + 1], h1v);
  }
  u32 o = (u32)f2bf(h0) | ((u32)f2bf(h1v) << 16);
  ((u32*)h2)[((u32)row << 4) + lt] = o;   // 16 lanes x u32 = 64B row
}

// ---------------------------------------------------------------------------
// Team-vectorized CSR SPMM (used for layer 2): TEAM = D/4 lanes per row.
template <int D, bool RELU>
__global__ __launch_bounds__(256) void spmm_csr_kernel(
    const int* __restrict__ rs, const u32* __restrict__ csr,
    const u16* __restrict__ in, const float* __restrict__ bias,
    u16* __restrict__ out, int M) {
  constexpr int TEAM = D / 4;
  constexpr int SH = (D == 64) ? 6 : 5;   // u16 elems per row = D = 1<<SH
  const int lt = threadIdx.x % TEAM;
  const int row = blockIdx.x * (256 / TEAM) + threadIdx.x / TEAM;
  if (row >= M) return;
  const int start = (row == 0) ? 0 : rs[row - 1];
  const int end = rs[row];
  const float qs = 1.f / 32768.f;
  const u16* inp = in + lt * 4;

  float a0 = 0.f, a1 = 0.f, a2 = 0.f, a3 = 0.f;
  int j = start;

  // head peel to 16B-aligned csr index
  int head = (4 - (start & 3)) & 3;
  if (head > end - start) head = end - start;
  for (int h = 0; h < head; ++h, ++j) {
    u32 pk = csr[j];
    uint2 w = *(const uint2*)(inp + ((pk >> 15) << SH));
    float v = (float)(pk & 32767u) * qs;
    a0 = fmaf(v, bf2f(w.x), a0); a1 = fmaf(v, bf2f_hi(w.x), a1);
    a2 = fmaf(v, bf2f(w.y), a2); a3 = fmaf(v, bf2f_hi(w.y), a3);
  }

  // 8-edge main loop: 2 independent csr uint4 + 8 gathers in flight
  for (; j + 8 <= end; j += 8) {
    uint4 pa = *(const uint4*)&csr[j];
    uint4 pb = *(const uint4*)&csr[j + 4];
    uint2 w0 = *(const uint2*)(inp + ((pa.x >> 15) << SH));
    uint2 w1 = *(const uint2*)(inp + ((pa.y >> 15) << SH));
    uint2 w2 = *(const uint2*)(inp + ((pa.z >> 15) << SH));
    uint2 w3 = *(const uint2*)(inp + ((pa.w >> 15) << SH));
    uint2 w4 = *(const uint2*)(inp + ((pb.x >> 15) << SH));
    uint2 w5 = *(const uint2*)(inp + ((pb.y >> 15) << SH));
    uint2 w6 = *(const uint2*)(inp + ((pb.z >> 15) << SH));
    uint2 w7 = *(const uint2*)(inp + ((pb.w >> 15) << SH));
    float v0 = (float)(pa.x & 32767u) * qs;
    float v1 = (float)(pa.y & 32767u) * qs;
    float v2 = (float)(pa.z & 32767u) * qs;
    float v3 = (float)(pa.w & 32767u) * qs;
    float v4 = (float)(pb.x & 32767u) * qs;
    float v5 = (float)(pb.y & 32767u) * qs;
    float v6 = (float)(pb.z & 32767u) * qs;
    float v7 = (float)(pb.w & 32767u) * qs;
    a0 = fmaf(v0, bf2f(w0.x), a0); a1 = fmaf(v0, bf2f_hi(w0.x), a1);
    a2 = fmaf(v0, bf2f(w0.y), a2); a3 = fmaf(v0, bf2f_hi(w0.y), a3);
    a0 = fmaf(v1, bf2f(w1.x), a0); a1 = fmaf(v1, bf2f_hi(w1.x), a1);
    a2 = fmaf(v1, bf2f(w1.y), a2); a3 = fmaf(v1, bf2f_hi(w1.y), a3);
    a0 = fmaf(v2, bf2f(w2.x), a0); a1 = fmaf(v2, bf2f_hi(w2.x), a1);
    a2 = fmaf(v2, bf2f(w2.y), a2); a3 = fmaf(v2, bf2f_hi(w2.y), a3);
    a0 = fmaf(v3, bf2f(w3.x), a0); a1 = fmaf(v3, bf2f_hi(w3.x), a1);
    a2 = fmaf(v3, bf2f(w3.y), a2); a3 = fmaf(v3, bf2f_hi(w3.y), a3);
    a0 = fmaf(v4, bf2f(w4.x), a0); a1 = fmaf(v4, bf2f_hi(w4.x), a1);
    a2 = fmaf(v4, bf2f(w4.y), a2); a3 = fmaf(v4, bf2f_hi(w4.y), a3);
    a0 = fmaf(v5, bf2f(w5.x), a0); a1 = fmaf(v5, bf2f_hi(w5.x), a1);
    a2 = fmaf(v5, bf2f(w5.y), a2); a3 = fmaf(v5, bf2f_hi(w5.y), a3);
    a0 = fmaf(v6, bf2f(w6.x), a0); a1 = fmaf(v6, bf2f_hi(w6.x), a1);
    a2 = fmaf(v6, bf2f(w6.y), a2); a3 = fmaf(v6, bf2f_hi(w6.y), a3);
    a0 = fmaf(v7, bf2f(w7.x), a0); a1 = fmaf(v7, bf2f_hi(w7.x), a1);
    a2 = fmaf(v7, bf2f(w7.y), a2); a3 = fmaf(v7, bf2f_hi(w7.y), a3);
  }

  for (; j + 4 <= end; j += 4) {
    uint4 p = *(const uint4*)&csr[j];
    uint2 w0 = *(const uint2*)(inp + ((p.x >> 15) << SH));
    uint2 w1 = *(const uint2*)(inp + ((p.y >> 15) << SH));
    uint2 w2 = *(const uint2*)(inp + ((p.z >> 15) << SH));
    uint2 w3 = *(const uint2*)(inp + ((p.w >> 15) << SH));
    float v0 = (float)(p.x & 32767u) * qs;
    float v1 = (float)(p.y & 32767u) * qs;
    float v2 = (float)(p.z & 32767u) * qs;
    float v3 = (float)(p.w & 32767u) * qs;
    a0 = fmaf(v0, bf2f(w0.x), a0); a1 = fmaf(v0, bf2f_hi(w0.x), a1);
    a2 = fmaf(v0, bf2f(w0.y), a2); a3 = fmaf(v0, bf2f_hi(w0.y), a3);
    a0 = fmaf(v1, bf2f(w1.x), a0); a1 = fmaf(v1, bf2f_hi(w1.x), a1);
    a2 = fmaf(v1, bf2f(w1.y), a2); a3 = fmaf(v1, bf2f_hi(w1.y), a3);
    a0 = fmaf(v2, bf2f(w2.x), a0); a1 = fmaf(v2, bf2f_hi(w2.x), a1);
    a2 = fmaf(v2, bf2f(w2.y), a2); a3 = fmaf(v2, bf2f_hi(w2.y), a3);
    a0 = fmaf(v3, bf2f(w3.x), a0); a1 = fmaf(v3, bf2f_hi(w3.x), a1);
    a2 = fmaf(v3, bf2f(w3.y), a2); a3 = fmaf(v3, bf2f_hi(w3.y), a3);
  }
  for (; j < end; ++j) {
    u32 pk = csr[j];
    uint2 w = *(const uint2*)(inp + ((pk >> 15) << SH));
    float v = (float)(pk & 32767u) * qs;
    a0 = fmaf(v, bf2f(w.x), a0); a1 = fmaf(v, bf2f_hi(w.x), a1);
    a2 = fmaf(v, bf2f(w.y), a2); a3 = fmaf(v, bf2f_hi(w.y), a3);
  }
  const float4 bv = *(const float4*)&bias[lt * 4];
  a0 += bv.x; a1 += bv.y; a2 += bv.z; a3 += bv.w;
  if (RELU) {
    a0 = fmaxf(a0, 0.f); a1 = fmaxf(a1, 0.f);
    a2 = fmaxf(a2, 0.f); a3 = fmaxf(a3, 0.f);
  }
  uint2 o;
  o.x = (u32)f2bf(a0) | ((u32)f2bf(a1) << 16);
  o.y = (u32)f2bf(a2) | ((u32)f2bf(a3) << 16);
  *(uint2*)&out[((u32)row << SH) + lt * 4] = o;
}

// ---------------------------------------------------------------------------
// Decoder: scores[e] = dot(z2[src], z2[dst]). 2 edges per thread,
// all 8 uint4 gathers issued before the dot-product chains.
__global__ __launch_bounds__(256) void decode_kernel(
    const int* __restrict__ ei, const u16* __restrict__ z2,
    float* __restrict__ out, int nE) {
  const int t = blockIdx.x * 256 + threadIdx.x;
  const int e0 = t * 2;
  if (e0 >= nE) return;
  const bool two = (e0 + 1 < nE);

  const int2 ss = *(const int2*)&ei[e0];
  const int2 dd = *(const int2*)&ei[nE + e0];

  const uint4* za = (const uint4*)(z2 + ((u32)ss.x << 5));
  const uint4* zb = (const uint4*)(z2 + ((u32)dd.x << 5));
  const uint4* zc = (const uint4*)(z2 + ((u32)(two ? ss.y : ss.x) << 5));
  const uint4* zd = (const uint4*)(z2 + ((u32)(two ? dd.y : dd.x) << 5));

  uint4 A[2], B[2], C[2], Dv[2];
  A[0] = za[0]; A[1] = za[1];
  B[0] = zb[0]; B[1] = zb[1];
  C[0] = zc[0]; C[1] = zc[1];
  Dv[0] = zd[0]; Dv[1] = zd[1];
  uint4 A2[2], B2[2], C2[2], D2[2];
  A2[0] = za[2]; A2[1] = za[3];
  B2[0] = zb[2]; B2[1] = zb[3];
  C2[0] = zc[2]; C2[1] = zc[3];
  D2[0] = zd[2]; D2[1] = zd[3];

  float acc0 = 0.f, acc1 = 0.f;
  float a8[8], b8[8];
#pragma unroll
  for (int c = 0; c < 2; ++c) {
    unpack8(A[c], a8); unpack8(B[c], b8);
#pragma unroll
    for (int k = 0; k < 8; ++k) acc0 = fmaf(a8[k], b8[k], acc0);
    unpack8(A2[c], a8); unpack8(B2[c], b8);
#pragma unroll
    for (int k = 0; k < 8; ++k) acc0 = fmaf(a8[k], b8[k], acc0);
    unpack8(C[c], a8); unpack8(Dv[c], b8);
#pragma unroll
    for (int k = 0; k < 8; ++k) acc1 = fmaf(a8[k], b8[k], acc1);
    unpack8(C2[c], a8); unpack8(D2[c], b8);
#pragma unroll
    for (int k = 0; k < 8; ++k) acc1 = fmaf(a8[k], b8[k], acc1);
  }
  out[e0] = acc0;
  if (two) out[e0 + 1] = acc1;
}

// ---------------------------------------------------------------------------
extern "C" void kernel_launch(void* const* d_in, const int* in_sizes, int n_in,
                              void* d_out, int out_size, void* d_ws, size_t ws_size,
                              hipStream_t stream) {
  const float* x       = (const float*)d_in[0];
  const int*   adj_src = (const int*)d_in[1];
  const int*   adj_dst = (const int*)d_in[2];
  const float* adj_val = (const float*)d_in[3];
  const int*   ei      = (const int*)d_in[4];
  const float* W1      = (const float*)d_in[5];
  const float* b1      = (const float*)d_in[6];
  const float* W2      = (const float*)d_in[7];
  const float* b2      = (const float*)d_in[8];

  const int M   = in_sizes[0] / D_IN;      // 100000
  const int nnz = in_sizes[1];             // 3200000
  const int nE  = in_sizes[4] / 2;         // 2000000

  const int NBUK = (M + BROWS - 1) / BROWS;  // 391

  // Workspace (76.8 MB):
  //   [0, 12.8):       csr packed u32
  //   [12.8, 38.4):    payload int2 (dead after sort) -> h1 bf16 [12.8,25.6),
  //                    h2 bf16 [25.6, 32.0)
  //   [38.4, 44.8):    z2 bf16 [M,32]
  //   [60.0, +32KB):   gswz (pre-swizzled W1 bf16 fragments)
  char* ws = (char*)d_ws;
  u32*   csr     = (u32*)(ws);
  int2*  payload = (int2*)(ws + (size_t)nnz * 4);
  u16*   h1      = (u16*)(ws + (size_t)nnz * 4);
  u16*   h2      = (u16*)(ws + (size_t)nnz * 4 + (size_t)M * D_HID * 2);
  u16*   z2      = (u16*)(ws + (size_t)nnz * 12);
  uint4* gswz    = (uint4*)(ws + 60ull * 1024 * 1024);

  // Small scratch in d_out (8 MB, dead until decode):
  int* rs    = (int*)d_out;                 // M ints
  int* bscan = (int*)d_out + 112 * 1024;    // NBUK+1 ints
  int* cur   = (int*)d_out + 120 * 1024;    // NBUK ints

  // --- W1 swizzle ---
  w1_swizzle_kernel<<<8, 256, 0, stream>>>(W1, gswz);

  // --- bucket partition ---
  hipMemsetAsync(bscan, 0, (size_t)(NBUK + 1) * 4, stream);
  bin_count<<<256, 256, 0, stream>>>(adj_dst, bscan, nnz, NBUK);
  bin_scan<<<1, 256, 0, stream>>>(bscan, cur, NBUK);
  partition_kernel<<<(nnz + TILE - 1) / TILE, PBS, 0, stream>>>(
      adj_src, adj_dst, adj_val, cur, payload, nnz, NBUK);

  // --- bucket-local counting sort -> packed CSR + rs ---
  bucket_sort_kernel<<<NBUK, SBS, 0, stream>>>(bscan, payload, csr, rs, M);

  // --- GEMM1 via MFMA ---
  gemm1_mfma_kernel<<<(M + 63) / 64, 256, 0, stream>>>(x, gswz, h1, M);

  // --- SPMM1 + b1 + ReLU + GEMM2 fused (16-lane teams) ---
  spmm1_gemm2_fused<<<(M + 15) / 16, 256, 0, stream>>>(
      rs, csr, h1, b1, W2, h2, M);

  // --- SPMM2 + b2 (8-lane teams) ---
  spmm_csr_kernel<D_EMB, false><<<(M + 31) / 32, 256, 0, stream>>>(
      rs, csr, h2, b2, z2, M);

  // --- Decode (2 edges/thread, overwrites d_out scratch) ---
  decode_kernel<<<(nE / 2 + 255) / 256, 256, 0, stream>>>(ei, z2, (float*)d_out, nE);
}

// Round 5
// 416.414 us; speedup vs baseline: 1.6938x; 1.0025x over previous
//
#include <hip/hip_runtime.h>
#include <hip/hip_bf16.h>

// GCN link predictor, Round 14: src-locality-ordered CSR.
// R13 postmortem: gemm2 fusion delivered (-16us, as predicted). spmm1_fused
// remains the largest kernel (~62us, FETCH 156MB @ 2.8TB/s, gather-service
// bound). h1 = 12.8MB >> 4MB per-XCD L2 and within-row src order is random,
// so concurrent teams spray the whole array. R14 sorts each row's edges by
// src-QUARTILE (bucket_sort now counts 1024 bins = dstlow x (src>>15)):
// concurrent teams then touch ~3.2MB of h1 at a time -> per-XCD L2 can hold
// the hot quartile. Same ordering benefits spmm2 (h2 quartile 1.6MB).
// Everything else verbatim R13.

#define D_IN  256
#define D_HID 64
#define D_EMB 32
#define BROWS 256       // dst-rows per bucket
#define NBUK_MAX 512    // >= ceil(M/BROWS) = 391
#define TILE  4096      // edges per partition tile
#define PBS   512       // partition block size (PER = 8)
#define SBS   1024      // bucket_sort block size

typedef unsigned short u16;
typedef unsigned int u32;
typedef __attribute__((ext_vector_type(8))) short short8;   // 8 bf16
typedef __attribute__((ext_vector_type(4))) float f32x4;

__device__ __forceinline__ float bf2f(u32 u) {
  return __uint_as_float((u & 0xFFFFu) << 16);
}
__device__ __forceinline__ float bf2f_hi(u32 u) {
  return __uint_as_float(u & 0xFFFF0000u);
}
__device__ __forceinline__ u16 f2bf(float f) {
  u32 x = __float_as_uint(f);
  x += 0x7FFFu + ((x >> 16) & 1u);  // RNE
  return (u16)(x >> 16);
}
__device__ __forceinline__ void unpack8(uint4 u, float* f) {
  f[0] = bf2f(u.x); f[1] = bf2f(u.x >> 16);
  f[2] = bf2f(u.y); f[3] = bf2f(u.y >> 16);
  f[4] = bf2f(u.z); f[5] = bf2f(u.z >> 16);
  f[6] = bf2f(u.w); f[7] = bf2f(u.w >> 16);
}

// ---------------------------------------------------------------------------
// One-time W1 swizzle: fp32 [256,64] -> bf16 B-fragments.
__global__ __launch_bounds__(256) void w1_swizzle_kernel(
    const float* __restrict__ W1, uint4* __restrict__ gswz) {
  const int s = blockIdx.x * 256 + threadIdx.x;  // 2048 slots
  const int lane = s & 63;
  const int kstep = (s >> 6) & 7;
  const int nt = s >> 9;
  const int col = nt * 16 + (lane & 15);
  const int kbase = kstep * 32 + (lane >> 4) * 8;
  u32 p[4];
  for (int jp = 0; jp < 4; ++jp) {
    u32 lo = f2bf(W1[(kbase + 2 * jp) * D_HID + col]);
    u32 hi = f2bf(W1[(kbase + 2 * jp + 1) * D_HID + col]);
    p[jp] = lo | (hi << 16);
  }
  gswz[s] = make_uint4(p[0], p[1], p[2], p[3]);
}

// ---------------------------------------------------------------------------
// Bucket histogram (LDS-staged).
__global__ __launch_bounds__(256) void bin_count(
    const int* __restrict__ dst, int* __restrict__ hist, int nnz, int nbuk) {
  __shared__ int h[NBUK_MAX];
  for (int i = threadIdx.x; i < nbuk; i += 256) h[i] = 0;
  __syncthreads();
  const int stride = gridDim.x * 256;
  for (int e = blockIdx.x * 256 + threadIdx.x; e < nnz; e += stride)
    atomicAdd(&h[dst[e] >> 8], 1);
  __syncthreads();
  for (int i = threadIdx.x; i < nbuk; i += 256) {
    int v = h[i];
    if (v) atomicAdd(&hist[i], v);
  }
}

// 1-block exclusive scan (in place), copy to cur, sentinel hist[n] = total.
__global__ __launch_bounds__(256) void bin_scan(
    int* __restrict__ hist, int* __restrict__ cur, int n) {
  __shared__ int sm[256];
  const int t = threadIdx.x;
  const int per = (n + 255) / 256;
  const int base = t * per;
  int loc[4];
  int s = 0;
  for (int i = 0; i < per; ++i) {
    int idx = base + i;
    int v = (idx < n) ? hist[idx] : 0;
    loc[i] = s;
    s += v;
  }
  sm[t] = s;
  __syncthreads();
  for (int off = 1; off < 256; off <<= 1) {
    int tmp = (t >= off) ? sm[t - off] : 0;
    __syncthreads();
    sm[t] += tmp;
    __syncthreads();
  }
  const int b0 = sm[t] - s;
  for (int i = 0; i < per; ++i) {
    int idx = base + i;
    if (idx < n) {
      int p = b0 + loc[i];
      hist[idx] = p;
      cur[idx] = p;
    }
  }
  if (t == 255) hist[n] = sm[255];
}

// ---------------------------------------------------------------------------
// Tile-staged partition, 512 threads, 40KB LDS => 4 blocks/CU (32 waves).
// payload: .x = src<<8 | dstlow, .y = bucket<<15 | q15(val).
__global__ __launch_bounds__(PBS) void partition_kernel(
    const int* __restrict__ src, const int* __restrict__ dst,
    const float* __restrict__ val, int* __restrict__ cur,
    int2* __restrict__ payload, int nnz, int nbuk) {
  __shared__ int2 stage[TILE];            // 32 KB
  __shared__ int hist[NBUK_MAX];          // 2 KB: counts -> local excl offsets
  __shared__ int lcur[NBUK_MAX];          // 2 KB
  __shared__ int gbase[NBUK_MAX];         // 2 KB
  __shared__ int sm[PBS];                 // 2 KB

  const int t = threadIdx.x;
  const long long base = (long long)blockIdx.x * TILE;
  const int cnt = min(TILE, (int)(nnz - base));

  for (int i = t; i < nbuk; i += PBS) hist[i] = 0;
  __syncthreads();

  constexpr int PER = TILE / PBS;  // 8
  int key[PER], vq[PER];
  short bk[PER];
  for (int i = 0; i < PER; ++i) {
    int idx = t + i * PBS;
    if (idx < cnt) {
      int d = dst[base + idx];
      int b = d >> 8;
      bk[i] = (short)b;
      key[i] = (src[base + idx] << 8) | (d & (BROWS - 1));
      int q = (int)(val[base + idx] * 32768.f + 0.5f);
      q = min(q, 32767);
      vq[i] = (b << 15) | q;
      atomicAdd(&hist[b], 1);
    } else {
      bk[i] = -1;
    }
  }
  __syncthreads();

  // scan hist (nbuk <= PBS) -> exclusive offsets; reserve global chunks
  {
    int c = (t < nbuk) ? hist[t] : 0;
    sm[t] = c;
    __syncthreads();
    for (int off = 1; off < PBS; off <<= 1) {
      int tmp = (t >= off) ? sm[t - off] : 0;
      __syncthreads();
      sm[t] += tmp;
      __syncthreads();
    }
    int excl = sm[t] - c;
    if (t < nbuk) {
      hist[t] = excl;
      lcur[t] = excl;
      if (c > 0) gbase[t] = atomicAdd(&cur[t], c);
    }
  }
  __syncthreads();

  // counting sort into stage
  for (int i = 0; i < PER; ++i) {
    if (bk[i] >= 0) {
      int p = atomicAdd(&lcur[bk[i]], 1);
      stage[p] = make_int2(key[i], vq[i]);
    }
  }
  __syncthreads();

  // contiguous run write-out (bucket recovered from .y)
  for (int i = t; i < cnt; i += PBS) {
    int2 pk = stage[i];
    int b = pk.y >> 15;
    payload[gbase[b] + (i - hist[b])] = pk;
  }
}

// ---------------------------------------------------------------------------
// Bucket-local counting sort -> 4B packed CSR (src:17 | q15) + inclusive rs.
// R14: 1024 bins = dstlow(8b) x src-quartile(2b = src>>15) so each row's
// edges are grouped by 3.2MB h1 quartile -> concurrent teams share L2 set.
__global__ __launch_bounds__(SBS) void bucket_sort_kernel(
    const int* __restrict__ bscan, const int2* __restrict__ payload,
    u32* __restrict__ csr, int* __restrict__ rs, int M) {
  __shared__ int cnt_s[BROWS * 4];  // 4 KB
  __shared__ int sm[BROWS * 4];     // 4 KB
  const int b = blockIdx.x;
  const int t = threadIdx.x;        // 0..1023
  const int start = bscan[b];
  const int end = bscan[b + 1];

  cnt_s[t] = 0;
  __syncthreads();
  for (int j = start + t; j < end; j += SBS) {
    int k = payload[j].x;           // src<<8 | dstlow
    int bin = ((k & (BROWS - 1)) << 2) | ((k >> 23) & 3);
    atomicAdd(&cnt_s[bin], 1);
  }
  __syncthreads();

  int v = cnt_s[t];
  sm[t] = v;
  __syncthreads();
  for (int off = 1; off < SBS; off <<= 1) {
    int tmp = (t >= off) ? sm[t - off] : 0;
    __syncthreads();
    sm[t] += tmp;
    __syncthreads();
  }
  // sm[t] = inclusive scan over bins
  if ((t & 3) == 3) {
    int row = b * BROWS + (t >> 2);
    if (row < M) rs[row] = start + sm[t];   // row end = end of its last bin
  }
  cnt_s[t] = start + sm[t] - v;             // exclusive cursor for bin t
  __syncthreads();

  for (int j = start + t; j < end; j += SBS) {
    int2 pk = payload[j];
    int bin = ((pk.x & (BROWS - 1)) << 2) | ((pk.x >> 23) & 3);
    int p = atomicAdd(&cnt_s[bin], 1);
    csr[p] = ((u32)(pk.x >> 8) << 15) | (u32)(pk.y & 32767);
  }
}

// ---------------------------------------------------------------------------
// GEMM1 via MFMA: h1[M,64](bf16) = x[M,256](f32 -> bf16) @ W1.
__global__ __launch_bounds__(256) void gemm1_mfma_kernel(
    const float* __restrict__ x, const uint4* __restrict__ gswz,
    u16* __restrict__ h1, int M) {
  const int tid = threadIdx.x;
  const int wv = tid >> 6;
  const int lane = tid & 63;
  const int quad = lane >> 4;
  const int m = lane & 15;

  const int rowbase = blockIdx.x * 64 + wv * 16;
  int arow = rowbase + m;
  if (arow >= M) arow = M - 1;

  f32x4 acc[4];
  for (int nt = 0; nt < 4; ++nt) acc[nt] = (f32x4){0.f, 0.f, 0.f, 0.f};

  const float* xrow = &x[(long long)arow * D_IN];

#pragma unroll
  for (int kstep = 0; kstep < 8; ++kstep) {
    const int kbase = kstep * 32 + quad * 8;
    float4 a0 = *(const float4*)&xrow[kbase];
    float4 a1 = *(const float4*)&xrow[kbase + 4];
    short8 af;
    af[0] = (short)f2bf(a0.x); af[1] = (short)f2bf(a0.y);
    af[2] = (short)f2bf(a0.z); af[3] = (short)f2bf(a0.w);
    af[4] = (short)f2bf(a1.x); af[5] = (short)f2bf(a1.y);
    af[6] = (short)f2bf(a1.z); af[7] = (short)f2bf(a1.w);
#pragma unroll
    for (int nt = 0; nt < 4; ++nt) {
      uint4 bu = gswz[(nt * 8 + kstep) * 64 + lane];
      short8 bf = *(short8*)&bu;
      acc[nt] = __builtin_amdgcn_mfma_f32_16x16x32_bf16(af, bf, acc[nt], 0, 0, 0);
    }
  }

#pragma unroll
  for (int nt = 0; nt < 4; ++nt) {
#pragma unroll
    for (int r = 0; r < 4; ++r) {
      int orow = rowbase + quad * 4 + r;
      if (orow < M)
        h1[(long long)orow * D_HID + nt * 16 + m] = f2bf(acc[nt][r]);
    }
  }
}

// ---------------------------------------------------------------------------
// SPMM1 + b1 + ReLU fused with GEMM2: h2[M,32] = relu(A@h1 + b1) @ W2.
// 16-lane teams; z1 row staged in padded LDS (68-float skew, conflict-free
// broadcast); W2 in 8KB LDS. Within-wave LDS producer->consumer (no barrier).
__global__ __launch_bounds__(256) void spmm1_gemm2_fused(
    const int* __restrict__ rs, const u32* __restrict__ csr,
    const u16* __restrict__ in, const float* __restrict__ b1,
    const float* __restrict__ W2, u16* __restrict__ h2, int M) {
  __shared__ float w2s[D_HID * D_EMB];   // 8 KB
  __shared__ float z1s[16][68];          // 4.25 KB, +4 skew per team row

  const int tid = threadIdx.x;
  for (int i = tid; i < D_HID * D_EMB / 4; i += 256)
    ((float4*)w2s)[i] = ((const float4*)W2)[i];
  __syncthreads();

  const int lt = tid & 15;
  const int tb = tid >> 4;                    // team in block (0..15)
  const int row = blockIdx.x * 16 + tb;
  if (row >= M) return;

  const int start = (row == 0) ? 0 : rs[row - 1];
  const int end = rs[row];
  const float qs = 1.f / 32768.f;
  const u16* inp = in + lt * 4;

  float a0 = 0.f, a1 = 0.f, a2 = 0.f, a3 = 0.f;
  int j = start;

  // head peel to 16B-aligned csr index
  int head = (4 - (start & 3)) & 3;
  if (head > end - start) head = end - start;
  for (int h = 0; h < head; ++h, ++j) {
    u32 pk = csr[j];
    uint2 w = *(const uint2*)(inp + ((pk >> 15) << 6));
    float v = (float)(pk & 32767u) * qs;
    a0 = fmaf(v, bf2f(w.x), a0); a1 = fmaf(v, bf2f_hi(w.x), a1);
    a2 = fmaf(v, bf2f(w.y), a2); a3 = fmaf(v, bf2f_hi(w.y), a3);
  }

  // 8-edge main loop: 2 independent csr uint4 + 8 gathers in flight
  for (; j + 8 <= end; j += 8) {
    uint4 pa = *(const uint4*)&csr[j];
    uint4 pb = *(const uint4*)&csr[j + 4];
    uint2 w0 = *(const uint2*)(inp + ((pa.x >> 15) << 6));
    uint2 w1 = *(const uint2*)(inp + ((pa.y >> 15) << 6));
    uint2 w2 = *(const uint2*)(inp + ((pa.z >> 15) << 6));
    uint2 w3 = *(const uint2*)(inp + ((pa.w >> 15) << 6));
    uint2 w4 = *(const uint2*)(inp + ((pb.x >> 15) << 6));
    uint2 w5 = *(const uint2*)(inp + ((pb.y >> 15) << 6));
    uint2 w6 = *(const uint2*)(inp + ((pb.z >> 15) << 6));
    uint2 w7 = *(const uint2*)(inp + ((pb.w >> 15) << 6));
    float v0 = (float)(pa.x & 32767u) * qs;
    float v1 = (float)(pa.y & 32767u) * qs;
    float v2 = (float)(pa.z & 32767u) * qs;
    float v3 = (float)(pa.w & 32767u) * qs;
    float v4 = (float)(pb.x & 32767u) * qs;
    float v5 = (float)(pb.y & 32767u) * qs;
    float v6 = (float)(pb.z & 32767u) * qs;
    float v7 = (float)(pb.w & 32767u) * qs;
    a0 = fmaf(v0, bf2f(w0.x), a0); a1 = fmaf(v0, bf2f_hi(w0.x), a1);
    a2 = fmaf(v0, bf2f(w0.y), a2); a3 = fmaf(v0, bf2f_hi(w0.y), a3);
    a0 = fmaf(v1, bf2f(w1.x), a0); a1 = fmaf(v1, bf2f_hi(w1.x), a1);
    a2 = fmaf(v1, bf2f(w1.y), a2); a3 = fmaf(v1, bf2f_hi(w1.y), a3);
    a0 = fmaf(v2, bf2f(w2.x), a0); a1 = fmaf(v2, bf2f_hi(w2.x), a1);
    a2 = fmaf(v2, bf2f(w2.y), a2); a3 = fmaf(v2, bf2f_hi(w2.y), a3);
    a0 = fmaf(v3, bf2f(w3.x), a0); a1 = fmaf(v3, bf2f_hi(w3.x), a1);
    a2 = fmaf(v3, bf2f(w3.y), a2); a3 = fmaf(v3, bf2f_hi(w3.y), a3);
    a0 = fmaf(v4, bf2f(w4.x), a0); a1 = fmaf(v4, bf2f_hi(w4.x), a1);
    a2 = fmaf(v4, bf2f(w4.y), a2); a3 = fmaf(v4, bf2f_hi(w4.y), a3);
    a0 = fmaf(v5, bf2f(w5.x), a0); a1 = fmaf(v5, bf2f_hi(w5.x), a1);
    a2 = fmaf(v5, bf2f(w5.y), a2); a3 = fmaf(v5, bf2f_hi(w5.y), a3);
    a0 = fmaf(v6, bf2f(w6.x), a0); a1 = fmaf(v6, bf2f_hi(w6.x), a1);
    a2 = fmaf(v6, bf2f(w6.y), a2); a3 = fmaf(v6, bf2f_hi(w6.y), a3);
    a0 = fmaf(v7, bf2f(w7.x), a0); a1 = fmaf(v7, bf2f_hi(w7.x), a1);
    a2 = fmaf(v7, bf2f(w7.y), a2); a3 = fmaf(v7, bf2f_hi(w7.y), a3);
  }

  for (; j + 4 <= end; j += 4) {
    uint4 p = *(const uint4*)&csr[j];
    uint2 w0 = *(const uint2*)(inp + ((p.x >> 15) << 6));
    uint2 w1 = *(const uint2*)(inp + ((p.y >> 15) << 6));
    uint2 w2 = *(const uint2*)(inp + ((p.z >> 15) << 6));
    uint2 w3 = *(const uint2*)(inp + ((p.w >> 15) << 6));
    float v0 = (float)(p.x & 32767u) * qs;
    float v1 = (float)(p.y & 32767u) * qs;
    float v2 = (float)(p.z & 32767u) * qs;
    float v3 = (float)(p.w & 32767u) * qs;
    a0 = fmaf(v0, bf2f(w0.x), a0); a1 = fmaf(v0, bf2f_hi(w0.x), a1);
    a2 = fmaf(v0, bf2f(w0.y), a2); a3 = fmaf(v0, bf2f_hi(w0.y), a3);
    a0 = fmaf(v1, bf2f(w1.x), a0); a1 = fmaf(v1, bf2f_hi(w1.x), a1);
    a2 = fmaf(v1, bf2f(w1.y), a2); a3 = fmaf(v1, bf2f_hi(w1.y), a3);
    a0 = fmaf(v2, bf2f(w2.x), a0); a1 = fmaf(v2, bf2f_hi(w2.x), a1);
    a2 = fmaf(v2, bf2f(w2.y), a2); a3 = fmaf(v2, bf2f_hi(w2.y), a3);
    a0 = fmaf(v3, bf2f(w3.x), a0); a1 = fmaf(v3, bf2f_hi(w3.x), a1);
    a2 = fmaf(v3, bf2f(w3.y), a2); a3 = fmaf(v3, bf2f_hi(w3.y), a3);
  }
  for (; j < end; ++j) {
    u32 pk = csr[j];
    uint2 w = *(const uint2*)(inp + ((pk >> 15) << 6));
    float v = (float)(pk & 32767u) * qs;
    a0 = fmaf(v, bf2f(w.x), a0); a1 = fmaf(v, bf2f_hi(w.x), a1);
    a2 = fmaf(v, bf2f(w.y), a2); a3 = fmaf(v, bf2f_hi(w.y), a3);
  }

  const float4 bv = *(const float4*)&b1[lt * 4];
  a0 = fmaxf(a0 + bv.x, 0.f);
  a1 = fmaxf(a1 + bv.y, 0.f);
  a2 = fmaxf(a2 + bv.z, 0.f);
  a3 = fmaxf(a3 + bv.w, 0.f);

  // --- fused GEMM2 epilogue: h2[row] = z1row @ W2 ---
  float* zrow = z1s[tb];
  zrow[lt * 4 + 0] = a0;
  zrow[lt * 4 + 1] = a1;
  zrow[lt * 4 + 2] = a2;
  zrow[lt * 4 + 3] = a3;
  // same wave: LDS ops in order, no barrier needed
  float h0 = 0.f, h1v = 0.f;
#pragma unroll
  for (int k = 0; k < D_HID; k += 4) {
    float4 z4 = *(const float4*)&zrow[k];
    h0  = fmaf(z4.x, w2s[(k + 0) * D_EMB + 2 * lt], h0);
    h1v = fmaf(z4.x, w2s[(k + 0) * D_EMB + 2 * lt + 1], h1v);
    h0  = fmaf(z4.y, w2s[(k + 1) * D_EMB + 2 * lt], h0);
    h1v = fmaf(z4.y, w2s[(k + 1) * D_EMB + 2 * lt + 1], h1v);
    h0  = fmaf(z4.z, w2s[(k + 2) * D_EMB + 2 * lt], h0);
    h1v = fmaf(z4.z, w2s[(k + 2) * D_EMB + 2 * lt + 1], h1v);
    h0  = fmaf(z4.w, w2s[(k + 3) * D_EMB + 2 * lt], h0);
    h1v = fmaf(z4.w, w2s[(k + 3) * D_EMB + 2 * lt + 1], h1v);
  }
  u32 o = (u32)f2bf(h0) | ((u32)f2bf(h1v) << 16);
  ((u32*)h2)[((u32)row << 4) + lt] = o;   // 16 lanes x u32 = 64B row
}

// ---------------------------------------------------------------------------
// Team-vectorized CSR SPMM (used for layer 2): TEAM = D/4 lanes per row.
template <int D, bool RELU>
__global__ __launch_bounds__(256) void spmm_csr_kernel(
    const int* __restrict__ rs, const u32* __restrict__ csr,
    const u16* __restrict__ in, const float* __restrict__ bias,
    u16* __restrict__ out, int M) {
  constexpr int TEAM = D / 4;
  constexpr int SH = (D == 64) ? 6 : 5;   // u16 elems per row = D = 1<<SH
  const int lt = threadIdx.x % TEAM;
  const int row = blockIdx.x * (256 / TEAM) + threadIdx.x / TEAM;
  if (row >= M) return;
  const int start = (row == 0) ? 0 : rs[row - 1];
  const int end = rs[row];
  const float qs = 1.f / 32768.f;
  const u16* inp = in + lt * 4;

  float a0 = 0.f, a1 = 0.f, a2 = 0.f, a3 = 0.f;
  int j = start;

  // head peel to 16B-aligned csr index
  int head = (4 - (start & 3)) & 3;
  if (head > end - start) head = end - start;
  for (int h = 0; h < head; ++h, ++j) {
    u32 pk = csr[j];
    uint2 w = *(const uint2*)(inp + ((pk >> 15) << SH));
    float v = (float)(pk & 32767u) * qs;
    a0 = fmaf(v, bf2f(w.x), a0); a1 = fmaf(v, bf2f_hi(w.x), a1);
    a2 = fmaf(v, bf2f(w.y), a2); a3 = fmaf(v, bf2f_hi(w.y), a3);
  }

  // 8-edge main loop: 2 independent csr uint4 + 8 gathers in flight
  for (; j + 8 <= end; j += 8) {
    uint4 pa = *(const uint4*)&csr[j];
    uint4 pb = *(const uint4*)&csr[j + 4];
    uint2 w0 = *(const uint2*)(inp + ((pa.x >> 15) << SH));
    uint2 w1 = *(const uint2*)(inp + ((pa.y >> 15) << SH));
    uint2 w2 = *(const uint2*)(inp + ((pa.z >> 15) << SH));
    uint2 w3 = *(const uint2*)(inp + ((pa.w >> 15) << SH));
    uint2 w4 = *(const uint2*)(inp + ((pb.x >> 15) << SH));
    uint2 w5 = *(const uint2*)(inp + ((pb.y >> 15) << SH));
    uint2 w6 = *(const uint2*)(inp + ((pb.z >> 15) << SH));
    uint2 w7 = *(const uint2*)(inp + ((pb.w >> 15) << SH));
    float v0 = (float)(pa.x & 32767u) * qs;
    float v1 = (float)(pa.y & 32767u) * qs;
    float v2 = (float)(pa.z & 32767u) * qs;
    float v3 = (float)(pa.w & 32767u) * qs;
    float v4 = (float)(pb.x & 32767u) * qs;
    float v5 = (float)(pb.y & 32767u) * qs;
    float v6 = (float)(pb.z & 32767u) * qs;
    float v7 = (float)(pb.w & 32767u) * qs;
    a0 = fmaf(v0, bf2f(w0.x), a0); a1 = fmaf(v0, bf2f_hi(w0.x), a1);
    a2 = fmaf(v0, bf2f(w0.y), a2); a3 = fmaf(v0, bf2f_hi(w0.y), a3);
    a0 = fmaf(v1, bf2f(w1.x), a0); a1 = fmaf(v1, bf2f_hi(w1.x), a1);
    a2 = fmaf(v1, bf2f(w1.y), a2); a3 = fmaf(v1, bf2f_hi(w1.y), a3);
    a0 = fmaf(v2, bf2f(w2.x), a0); a1 = fmaf(v2, bf2f_hi(w2.x), a1);
    a2 = fmaf(v2, bf2f(w2.y), a2); a3 = fmaf(v2, bf2f_hi(w2.y), a3);
    a0 = fmaf(v3, bf2f(w3.x), a0); a1 = fmaf(v3, bf2f_hi(w3.x), a1);
    a2 = fmaf(v3, bf2f(w3.y), a2); a3 = fmaf(v3, bf2f_hi(w3.y), a3);
    a0 = fmaf(v4, bf2f(w4.x), a0); a1 = fmaf(v4, bf2f_hi(w4.x), a1);
    a2 = fmaf(v4, bf2f(w4.y), a2); a3 = fmaf(v4, bf2f_hi(w4.y), a3);
    a0 = fmaf(v5, bf2f(w5.x), a0); a1 = fmaf(v5, bf2f_hi(w5.x), a1);
    a2 = fmaf(v5, bf2f(w5.y), a2); a3 = fmaf(v5, bf2f_hi(w5.y), a3);
    a0 = fmaf(v6, bf2f(w6.x), a0); a1 = fmaf(v6, bf2f_hi(w6.x), a1);
    a2 = fmaf(v6, bf2f(w6.y), a2); a3 = fmaf(v6, bf2f_hi(w6.y), a3);
    a0 = fmaf(v7, bf2f(w7.x), a0); a1 = fmaf(v7, bf2f_hi(w7.x), a1);
    a2 = fmaf(v7, bf2f(w7.y), a2); a3 = fmaf(v7, bf2f_hi(w7.y), a3);
  }

  for (; j + 4 <= end; j += 4) {
    uint4 p = *(const uint4*)&csr[j];
    uint2 w0 = *(const uint2*)(inp + ((p.x >> 15) << SH));
    uint2 w1 = *(const uint2*)(inp + ((p.y >> 15) << SH));
    uint2 w2 = *(const uint2*)(inp + ((p.z >> 15) << SH));
    uint2 w3 = *(const uint2*)(inp + ((p.w >> 15) << SH));
    float v0 = (float)(p.x & 32767u) * qs;
    float v1 = (float)(p.y & 32767u) * qs;
    float v2 = (float)(p.z & 32767u) * qs;
    float v3 = (float)(p.w & 32767u) * qs;
    a0 = fmaf(v0, bf2f(w0.x), a0); a1 = fmaf(v0, bf2f_hi(w0.x), a1);
    a2 = fmaf(v0, bf2f(w0.y), a2); a3 = fmaf(v0, bf2f_hi(w0.y), a3);
    a0 = fmaf(v1, bf2f(w1.x), a0); a1 = fmaf(v1, bf2f_hi(w1.x), a1);
    a2 = fmaf(v1, bf2f(w1.y), a2); a3 = fmaf(v1, bf2f_hi(w1.y), a3);
    a0 = fmaf(v2, bf2f(w2.x), a0); a1 = fmaf(v2, bf2f_hi(w2.x), a1);
    a2 = fmaf(v2, bf2f(w2.y), a2); a3 = fmaf(v2, bf2f_hi(w2.y), a3);
    a0 = fmaf(v3, bf2f(w3.x), a0); a1 = fmaf(v3, bf2f_hi(w3.x), a1);
    a2 = fmaf(v3, bf2f(w3.y), a2); a3 = fmaf(v3, bf2f_hi(w3.y), a3);
  }
  for (; j < end; ++j) {
    u32 pk = csr[j];
    uint2 w = *(const uint2*)(inp + ((pk >> 15) << SH));
    float v = (float)(pk & 32767u) * qs;
    a0 = fmaf(v, bf2f(w.x), a0); a1 = fmaf(v, bf2f_hi(w.x), a1);
    a2 = fmaf(v, bf2f(w.y), a2); a3 = fmaf(v, bf2f_hi(w.y), a3);
  }
  const float4 bv = *(const float4*)&bias[lt * 4];
  a0 += bv.x; a1 += bv.y; a2 += bv.z; a3 += bv.w;
  if (RELU) {
    a0 = fmaxf(a0, 0.f); a1 = fmaxf(a1, 0.f);
    a2 = fmaxf(a2, 0.f); a3 = fmaxf(a3, 0.f);
  }
  uint2 o;
  o.x = (u32)f2bf(a0) | ((u32)f2bf(a1) << 16);
  o.y = (u32)f2bf(a2) | ((u32)f2bf(a3) << 16);
  *(uint2*)&out[((u32)row << SH) + lt * 4] = o;
}

// ---------------------------------------------------------------------------
// Decoder: scores[e] = dot(z2[src], z2[dst]). 2 edges per thread,
// all 8 uint4 gathers issued before the dot-product chains.
__global__ __launch_bounds__(256) void decode_kernel(
    const int* __restrict__ ei, const u16* __restrict__ z2,
    float* __restrict__ out, int nE) {
  const int t = blockIdx.x * 256 + threadIdx.x;
  const int e0 = t * 2;
  if (e0 >= nE) return;
  const bool two = (e0 + 1 < nE);

  const int2 ss = *(const int2*)&ei[e0];
  const int2 dd = *(const int2*)&ei[nE + e0];

  const uint4* za = (const uint4*)(z2 + ((u32)ss.x << 5));
  const uint4* zb = (const uint4*)(z2 + ((u32)dd.x << 5));
  const uint4* zc = (const uint4*)(z2 + ((u32)(two ? ss.y : ss.x) << 5));
  const uint4* zd = (const uint4*)(z2 + ((u32)(two ? dd.y : dd.x) << 5));

  uint4 A[2], B[2], C[2], Dv[2];
  A[0] = za[0]; A[1] = za[1];
  B[0] = zb[0]; B[1] = zb[1];
  C[0] = zc[0]; C[1] = zc[1];
  Dv[0] = zd[0]; Dv[1] = zd[1];
  uint4 A2[2], B2[2], C2[2], D2[2];
  A2[0] = za[2]; A2[1] = za[3];
  B2[0] = zb[2]; B2[1] = zb[3];
  C2[0] = zc[2]; C2[1] = zc[3];
  D2[0] = zd[2]; D2[1] = zd[3];

  float acc0 = 0.f, acc1 = 0.f;
  float a8[8], b8[8];
#pragma unroll
  for (int c = 0; c < 2; ++c) {
    unpack8(A[c], a8); unpack8(B[c], b8);
#pragma unroll
    for (int k = 0; k < 8; ++k) acc0 = fmaf(a8[k], b8[k], acc0);
    unpack8(A2[c], a8); unpack8(B2[c], b8);
#pragma unroll
    for (int k = 0; k < 8; ++k) acc0 = fmaf(a8[k], b8[k], acc0);
    unpack8(C[c], a8); unpack8(Dv[c], b8);
#pragma unroll
    for (int k = 0; k < 8; ++k) acc1 = fmaf(a8[k], b8[k], acc1);
    unpack8(C2[c], a8); unpack8(D2[c], b8);
#pragma unroll
    for (int k = 0; k < 8; ++k) acc1 = fmaf(a8[k], b8[k], acc1);
  }
  out[e0] = acc0;
  if (two) out[e0 + 1] = acc1;
}

// ---------------------------------------------------------------------------
extern "C" void kernel_launch(void* const* d_in, const int* in_sizes, int n_in,
                              void* d_out, int out_size, void* d_ws, size_t ws_size,
                              hipStream_t stream) {
  const float* x       = (const float*)d_in[0];
  const int*   adj_src = (const int*)d_in[1];
  const int*   adj_dst = (const int*)d_in[2];
  const float* adj_val = (const float*)d_in[3];
  const int*   ei      = (const int*)d_in[4];
  const float* W1      = (const float*)d_in[5];
  const float* b1      = (const float*)d_in[6];
  const float* W2      = (const float*)d_in[7];
  const float* b2      = (const float*)d_in[8];

  const int M   = in_sizes[0] / D_IN;      // 100000
  const int nnz = in_sizes[1];             // 3200000
  const int nE  = in_sizes[4] / 2;         // 2000000

  const int NBUK = (M + BROWS - 1) / BROWS;  // 391

  // Workspace (76.8 MB):
  //   [0, 12.8):       csr packed u32
  //   [12.8, 38.4):    payload int2 (dead after sort) -> h1 bf16 [12.8,25.6),
  //                    h2 bf16 [25.6, 32.0)
  //   [38.4, 44.8):    z2 bf16 [M,32]
  //   [60.0, +32KB):   gswz (pre-swizzled W1 bf16 fragments)
  char* ws = (char*)d_ws;
  u32*   csr     = (u32*)(ws);
  int2*  payload = (int2*)(ws + (size_t)nnz * 4);
  u16*   h1      = (u16*)(ws + (size_t)nnz * 4);
  u16*   h2      = (u16*)(ws + (size_t)nnz * 4 + (size_t)M * D_HID * 2);
  u16*   z2      = (u16*)(ws + (size_t)nnz * 12);
  uint4* gswz    = (uint4*)(ws + 60ull * 1024 * 1024);

  // Small scratch in d_out (8 MB, dead until decode):
  int* rs    = (int*)d_out;                 // M ints
  int* bscan = (int*)d_out + 112 * 1024;    // NBUK+1 ints
  int* cur   = (int*)d_out + 120 * 1024;    // NBUK ints

  // --- W1 swizzle ---
  w1_swizzle_kernel<<<8, 256, 0, stream>>>(W1, gswz);

  // --- bucket partition ---
  hipMemsetAsync(bscan, 0, (size_t)(NBUK + 1) * 4, stream);
  bin_count<<<256, 256, 0, stream>>>(adj_dst, bscan, nnz, NBUK);
  bin_scan<<<1, 256, 0, stream>>>(bscan, cur, NBUK);
  partition_kernel<<<(nnz + TILE - 1) / TILE, PBS, 0, stream>>>(
      adj_src, adj_dst, adj_val, cur, payload, nnz, NBUK);

  // --- bucket-local counting sort (dstlow x src-quartile bins) ---
  bucket_sort_kernel<<<NBUK, SBS, 0, stream>>>(bscan, payload, csr, rs, M);

  // --- GEMM1 via MFMA ---
  gemm1_mfma_kernel<<<(M + 63) / 64, 256, 0, stream>>>(x, gswz, h1, M);

  // --- SPMM1 + b1 + ReLU + GEMM2 fused (16-lane teams) ---
  spmm1_gemm2_fused<<<(M + 15) / 16, 256, 0, stream>>>(
      rs, csr, h1, b1, W2, h2, M);

  // --- SPMM2 + b2 (8-lane teams) ---
  spmm_csr_kernel<D_EMB, false><<<(M + 31) / 32, 256, 0, stream>>>(
      rs, csr, h2, b2, z2, M);

  // --- Decode (2 edges/thread, overwrites d_out scratch) ---
  decode_kernel<<<(nE / 2 + 255) / 256, 256, 0, stream>>>(ei, z2, (float*)d_out, nE);
}

// Round 6
// 415.331 us; speedup vs baseline: 1.6982x; 1.0026x over previous
//
#include <hip/hip_runtime.h>
#include <hip/hip_bf16.h>

// GCN link predictor, Round 15: h1 in FP8 e4m3 (OCP, native gfx950 cvt).
// R14 postmortem: src-quartile ordering alone was neutral (FETCH 156->150MB,
// not ~100 as predicted) - teams aren't phase-aligned and 3.2MB chunks were
// marginal vs 4MB L2. R15 halves the gather itself: h1 stored as fp8 e4m3
// (row = 64B = ONE cache line vs two; footprint 12.8->6.4MB; quartile chunk
// 1.6MB now truly L2-resident -> R14's ordering composes). Gather decode is
// cheaper too: u32 load + 2x v_cvt_pk_f32_fp8 replaces uint2 + 4 bit-ops.
// gemm1 stores u8 (same 16 scalar stores/lane, half bytes). Accuracy: h1
// |val|<~8 << 448, ~3% rel quant -> scores err ~20-100 abs vs budget 512.
// Everything else verbatim R14 (sort pipeline, fused gemm2 epilogue, spmm2
// bf16, decode).

#define D_IN  256
#define D_HID 64
#define D_EMB 32
#define BROWS 256       // dst-rows per bucket
#define NBUK_MAX 512    // >= ceil(M/BROWS) = 391
#define TILE  4096      // edges per partition tile
#define PBS   512       // partition block size (PER = 8)
#define SBS   1024      // bucket_sort block size

typedef unsigned char u8;
typedef unsigned short u16;
typedef unsigned int u32;
typedef __attribute__((ext_vector_type(8))) short short8;   // 8 bf16
typedef __attribute__((ext_vector_type(4))) float f32x4;
typedef __attribute__((ext_vector_type(2))) float f32x2;

__device__ __forceinline__ float bf2f(u32 u) {
  return __uint_as_float((u & 0xFFFFu) << 16);
}
__device__ __forceinline__ float bf2f_hi(u32 u) {
  return __uint_as_float(u & 0xFFFF0000u);
}
__device__ __forceinline__ u16 f2bf(float f) {
  u32 x = __float_as_uint(f);
  x += 0x7FFFu + ((x >> 16) & 1u);  // RNE
  return (u16)(x >> 16);
}
__device__ __forceinline__ void unpack8(uint4 u, float* f) {
  f[0] = bf2f(u.x); f[1] = bf2f(u.x >> 16);
  f[2] = bf2f(u.y); f[3] = bf2f(u.y >> 16);
  f[4] = bf2f(u.z); f[5] = bf2f(u.z >> 16);
  f[6] = bf2f(u.w); f[7] = bf2f(u.w >> 16);
}

// ---------------------------------------------------------------------------
// One-time W1 swizzle: fp32 [256,64] -> bf16 B-fragments.
__global__ __launch_bounds__(256) void w1_swizzle_kernel(
    const float* __restrict__ W1, uint4* __restrict__ gswz) {
  const int s = blockIdx.x * 256 + threadIdx.x;  // 2048 slots
  const int lane = s & 63;
  const int kstep = (s >> 6) & 7;
  const int nt = s >> 9;
  const int col = nt * 16 + (lane & 15);
  const int kbase = kstep * 32 + (lane >> 4) * 8;
  u32 p[4];
  for (int jp = 0; jp < 4; ++jp) {
    u32 lo = f2bf(W1[(kbase + 2 * jp) * D_HID + col]);
    u32 hi = f2bf(W1[(kbase + 2 * jp + 1) * D_HID + col]);
    p[jp] = lo | (hi << 16);
  }
  gswz[s] = make_uint4(p[0], p[1], p[2], p[3]);
}

// ---------------------------------------------------------------------------
// Bucket histogram (LDS-staged).
__global__ __launch_bounds__(256) void bin_count(
    const int* __restrict__ dst, int* __restrict__ hist, int nnz, int nbuk) {
  __shared__ int h[NBUK_MAX];
  for (int i = threadIdx.x; i < nbuk; i += 256) h[i] = 0;
  __syncthreads();
  const int stride = gridDim.x * 256;
  for (int e = blockIdx.x * 256 + threadIdx.x; e < nnz; e += stride)
    atomicAdd(&h[dst[e] >> 8], 1);
  __syncthreads();
  for (int i = threadIdx.x; i < nbuk; i += 256) {
    int v = h[i];
    if (v) atomicAdd(&hist[i], v);
  }
}

// 1-block exclusive scan (in place), copy to cur, sentinel hist[n] = total.
__global__ __launch_bounds__(256) void bin_scan(
    int* __restrict__ hist, int* __restrict__ cur, int n) {
  __shared__ int sm[256];
  const int t = threadIdx.x;
  const int per = (n + 255) / 256;
  const int base = t * per;
  int loc[4];
  int s = 0;
  for (int i = 0; i < per; ++i) {
    int idx = base + i;
    int v = (idx < n) ? hist[idx] : 0;
    loc[i] = s;
    s += v;
  }
  sm[t] = s;
  __syncthreads();
  for (int off = 1; off < 256; off <<= 1) {
    int tmp = (t >= off) ? sm[t - off] : 0;
    __syncthreads();
    sm[t] += tmp;
    __syncthreads();
  }
  const int b0 = sm[t] - s;
  for (int i = 0; i < per; ++i) {
    int idx = base + i;
    if (idx < n) {
      int p = b0 + loc[i];
      hist[idx] = p;
      cur[idx] = p;
    }
  }
  if (t == 255) hist[n] = sm[255];
}

// ---------------------------------------------------------------------------
// Tile-staged partition, 512 threads, 40KB LDS => 4 blocks/CU (32 waves).
// payload: .x = src<<8 | dstlow, .y = bucket<<15 | q15(val).
__global__ __launch_bounds__(PBS) void partition_kernel(
    const int* __restrict__ src, const int* __restrict__ dst,
    const float* __restrict__ val, int* __restrict__ cur,
    int2* __restrict__ payload, int nnz, int nbuk) {
  __shared__ int2 stage[TILE];            // 32 KB
  __shared__ int hist[NBUK_MAX];          // 2 KB: counts -> local excl offsets
  __shared__ int lcur[NBUK_MAX];          // 2 KB
  __shared__ int gbase[NBUK_MAX];         // 2 KB
  __shared__ int sm[PBS];                 // 2 KB

  const int t = threadIdx.x;
  const long long base = (long long)blockIdx.x * TILE;
  const int cnt = min(TILE, (int)(nnz - base));

  for (int i = t; i < nbuk; i += PBS) hist[i] = 0;
  __syncthreads();

  constexpr int PER = TILE / PBS;  // 8
  int key[PER], vq[PER];
  short bk[PER];
  for (int i = 0; i < PER; ++i) {
    int idx = t + i * PBS;
    if (idx < cnt) {
      int d = dst[base + idx];
      int b = d >> 8;
      bk[i] = (short)b;
      key[i] = (src[base + idx] << 8) | (d & (BROWS - 1));
      int q = (int)(val[base + idx] * 32768.f + 0.5f);
      q = min(q, 32767);
      vq[i] = (b << 15) | q;
      atomicAdd(&hist[b], 1);
    } else {
      bk[i] = -1;
    }
  }
  __syncthreads();

  // scan hist (nbuk <= PBS) -> exclusive offsets; reserve global chunks
  {
    int c = (t < nbuk) ? hist[t] : 0;
    sm[t] = c;
    __syncthreads();
    for (int off = 1; off < PBS; off <<= 1) {
      int tmp = (t >= off) ? sm[t - off] : 0;
      __syncthreads();
      sm[t] += tmp;
      __syncthreads();
    }
    int excl = sm[t] - c;
    if (t < nbuk) {
      hist[t] = excl;
      lcur[t] = excl;
      if (c > 0) gbase[t] = atomicAdd(&cur[t], c);
    }
  }
  __syncthreads();

  // counting sort into stage
  for (int i = 0; i < PER; ++i) {
    if (bk[i] >= 0) {
      int p = atomicAdd(&lcur[bk[i]], 1);
      stage[p] = make_int2(key[i], vq[i]);
    }
  }
  __syncthreads();

  // contiguous run write-out (bucket recovered from .y)
  for (int i = t; i < cnt; i += PBS) {
    int2 pk = stage[i];
    int b = pk.y >> 15;
    payload[gbase[b] + (i - hist[b])] = pk;
  }
}

// ---------------------------------------------------------------------------
// Bucket-local counting sort -> 4B packed CSR (src:17 | q15) + inclusive rs.
// 1024 bins = dstlow(8b) x src-quartile(2b): rows' edges grouped by h1
// quartile (1.6MB in fp8 -> L2-resident hot chunk).
__global__ __launch_bounds__(SBS) void bucket_sort_kernel(
    const int* __restrict__ bscan, const int2* __restrict__ payload,
    u32* __restrict__ csr, int* __restrict__ rs, int M) {
  __shared__ int cnt_s[BROWS * 4];  // 4 KB
  __shared__ int sm[BROWS * 4];     // 4 KB
  const int b = blockIdx.x;
  const int t = threadIdx.x;        // 0..1023
  const int start = bscan[b];
  const int end = bscan[b + 1];

  cnt_s[t] = 0;
  __syncthreads();
  for (int j = start + t; j < end; j += SBS) {
    int k = payload[j].x;           // src<<8 | dstlow
    int bin = ((k & (BROWS - 1)) << 2) | ((k >> 23) & 3);
    atomicAdd(&cnt_s[bin], 1);
  }
  __syncthreads();

  int v = cnt_s[t];
  sm[t] = v;
  __syncthreads();
  for (int off = 1; off < SBS; off <<= 1) {
    int tmp = (t >= off) ? sm[t - off] : 0;
    __syncthreads();
    sm[t] += tmp;
    __syncthreads();
  }
  // sm[t] = inclusive scan over bins
  if ((t & 3) == 3) {
    int row = b * BROWS + (t >> 2);
    if (row < M) rs[row] = start + sm[t];   // row end = end of its last bin
  }
  cnt_s[t] = start + sm[t] - v;             // exclusive cursor for bin t
  __syncthreads();

  for (int j = start + t; j < end; j += SBS) {
    int2 pk = payload[j];
    int bin = ((pk.x & (BROWS - 1)) << 2) | ((pk.x >> 23) & 3);
    int p = atomicAdd(&cnt_s[bin], 1);
    csr[p] = ((u32)(pk.x >> 8) << 15) | (u32)(pk.y & 32767);
  }
}

// ---------------------------------------------------------------------------
// GEMM1 via MFMA: h1[M,64](fp8 e4m3) = x[M,256](f32 -> bf16) @ W1.
__global__ __launch_bounds__(256) void gemm1_mfma_kernel(
    const float* __restrict__ x, const uint4* __restrict__ gswz,
    u8* __restrict__ h1, int M) {
  const int tid = threadIdx.x;
  const int wv = tid >> 6;
  const int lane = tid & 63;
  const int quad = lane >> 4;
  const int m = lane & 15;

  const int rowbase = blockIdx.x * 64 + wv * 16;
  int arow = rowbase + m;
  if (arow >= M) arow = M - 1;

  f32x4 acc[4];
  for (int nt = 0; nt < 4; ++nt) acc[nt] = (f32x4){0.f, 0.f, 0.f, 0.f};

  const float* xrow = &x[(long long)arow * D_IN];

#pragma unroll
  for (int kstep = 0; kstep < 8; ++kstep) {
    const int kbase = kstep * 32 + quad * 8;
    float4 a0 = *(const float4*)&xrow[kbase];
    float4 a1 = *(const float4*)&xrow[kbase + 4];
    short8 af;
    af[0] = (short)f2bf(a0.x); af[1] = (short)f2bf(a0.y);
    af[2] = (short)f2bf(a0.z); af[3] = (short)f2bf(a0.w);
    af[4] = (short)f2bf(a1.x); af[5] = (short)f2bf(a1.y);
    af[6] = (short)f2bf(a1.z); af[7] = (short)f2bf(a1.w);
#pragma unroll
    for (int nt = 0; nt < 4; ++nt) {
      uint4 bu = gswz[(nt * 8 + kstep) * 64 + lane];
      short8 bf = *(short8*)&bu;
      acc[nt] = __builtin_amdgcn_mfma_f32_16x16x32_bf16(af, bf, acc[nt], 0, 0, 0);
    }
  }

#pragma unroll
  for (int nt = 0; nt < 4; ++nt) {
#pragma unroll
    for (int r = 0; r < 4; ++r) {
      int orow = rowbase + quad * 4 + r;
      if (orow < M) {
        int pk8 = __builtin_amdgcn_cvt_pk_fp8_f32(acc[nt][r], 0.f, 0, false);
        h1[(u32)orow * D_HID + nt * 16 + m] = (u8)(pk8 & 0xFF);
      }
    }
  }
}

// ---------------------------------------------------------------------------
// SPMM1 + b1 + ReLU fused with GEMM2: h2[M,32] = relu(A@h1 + b1) @ W2.
// h1 is fp8 e4m3: each 16-lane team gathers one u32 (4 fp8) per lane = 64B
// row; decode = 2x v_cvt_pk_f32_fp8. z1 row staged in padded LDS; W2 in 8KB
// LDS. Within-wave LDS producer->consumer (no barrier).
__global__ __launch_bounds__(256) void spmm1_gemm2_fused(
    const int* __restrict__ rs, const u32* __restrict__ csr,
    const u8* __restrict__ in, const float* __restrict__ b1,
    const float* __restrict__ W2, u16* __restrict__ h2, int M) {
  __shared__ float w2s[D_HID * D_EMB];   // 8 KB
  __shared__ float z1s[16][68];          // 4.25 KB, +4 skew per team row

  const int tid = threadIdx.x;
  for (int i = tid; i < D_HID * D_EMB / 4; i += 256)
    ((float4*)w2s)[i] = ((const float4*)W2)[i];
  __syncthreads();

  const int lt = tid & 15;
  const int tb = tid >> 4;                    // team in block (0..15)
  const int row = blockIdx.x * 16 + tb;
  if (row >= M) return;

  const int start = (row == 0) ? 0 : rs[row - 1];
  const int end = rs[row];
  const float qs = 1.f / 32768.f;
  const u8* inp = in + lt * 4;

  float a0 = 0.f, a1 = 0.f, a2 = 0.f, a3 = 0.f;
  int j = start;

#define GATHER_FMA(PK)                                                \
  {                                                                   \
    u32 wq = *(const u32*)(inp + (((PK) >> 15) << 6));                \
    float v = (float)((PK) & 32767u) * qs;                            \
    f32x2 lo = __builtin_amdgcn_cvt_pk_f32_fp8(wq, false);            \
    f32x2 hi = __builtin_amdgcn_cvt_pk_f32_fp8(wq, true);             \
    a0 = fmaf(v, lo.x, a0); a1 = fmaf(v, lo.y, a1);                   \
    a2 = fmaf(v, hi.x, a2); a3 = fmaf(v, hi.y, a3);                   \
  }

  // head peel to 16B-aligned csr index
  int head = (4 - (start & 3)) & 3;
  if (head > end - start) head = end - start;
  for (int h = 0; h < head; ++h, ++j) {
    u32 pk = csr[j];
    GATHER_FMA(pk);
  }

  // 8-edge main loop: 2 independent csr uint4 + 8 gathers in flight
  for (; j + 8 <= end; j += 8) {
    uint4 pa = *(const uint4*)&csr[j];
    uint4 pb = *(const uint4*)&csr[j + 4];
    u32 w0 = *(const u32*)(inp + ((pa.x >> 15) << 6));
    u32 w1 = *(const u32*)(inp + ((pa.y >> 15) << 6));
    u32 w2 = *(const u32*)(inp + ((pa.z >> 15) << 6));
    u32 w3 = *(const u32*)(inp + ((pa.w >> 15) << 6));
    u32 w4 = *(const u32*)(inp + ((pb.x >> 15) << 6));
    u32 w5 = *(const u32*)(inp + ((pb.y >> 15) << 6));
    u32 w6 = *(const u32*)(inp + ((pb.z >> 15) << 6));
    u32 w7 = *(const u32*)(inp + ((pb.w >> 15) << 6));
    float v0 = (float)(pa.x & 32767u) * qs;
    float v1 = (float)(pa.y & 32767u) * qs;
    float v2 = (float)(pa.z & 32767u) * qs;
    float v3 = (float)(pa.w & 32767u) * qs;
    float v4 = (float)(pb.x & 32767u) * qs;
    float v5 = (float)(pb.y & 32767u) * qs;
    float v6 = (float)(pb.z & 32767u) * qs;
    float v7 = (float)(pb.w & 32767u) * qs;
    f32x2 l0 = __builtin_amdgcn_cvt_pk_f32_fp8(w0, false);
    f32x2 h0 = __builtin_amdgcn_cvt_pk_f32_fp8(w0, true);
    f32x2 l1 = __builtin_amdgcn_cvt_pk_f32_fp8(w1, false);
    f32x2 h1f = __builtin_amdgcn_cvt_pk_f32_fp8(w1, true);
    f32x2 l2 = __builtin_amdgcn_cvt_pk_f32_fp8(w2, false);
    f32x2 h2f = __builtin_amdgcn_cvt_pk_f32_fp8(w2, true);
    f32x2 l3 = __builtin_amdgcn_cvt_pk_f32_fp8(w3, false);
    f32x2 h3 = __builtin_amdgcn_cvt_pk_f32_fp8(w3, true);
    f32x2 l4 = __builtin_amdgcn_cvt_pk_f32_fp8(w4, false);
    f32x2 h4 = __builtin_amdgcn_cvt_pk_f32_fp8(w4, true);
    f32x2 l5 = __builtin_amdgcn_cvt_pk_f32_fp8(w5, false);
    f32x2 h5 = __builtin_amdgcn_cvt_pk_f32_fp8(w5, true);
    f32x2 l6 = __builtin_amdgcn_cvt_pk_f32_fp8(w6, false);
    f32x2 h6 = __builtin_amdgcn_cvt_pk_f32_fp8(w6, true);
    f32x2 l7 = __builtin_amdgcn_cvt_pk_f32_fp8(w7, false);
    f32x2 h7 = __builtin_amdgcn_cvt_pk_f32_fp8(w7, true);
    a0 = fmaf(v0, l0.x, a0); a1 = fmaf(v0, l0.y, a1);
    a2 = fmaf(v0, h0.x, a2); a3 = fmaf(v0, h0.y, a3);
    a0 = fmaf(v1, l1.x, a0); a1 = fmaf(v1, l1.y, a1);
    a2 = fmaf(v1, h1f.x, a2); a3 = fmaf(v1, h1f.y, a3);
    a0 = fmaf(v2, l2.x, a0); a1 = fmaf(v2, l2.y, a1);
    a2 = fmaf(v2, h2f.x, a2); a3 = fmaf(v2, h2f.y, a3);
    a0 = fmaf(v3, l3.x, a0); a1 = fmaf(v3, l3.y, a1);
    a2 = fmaf(v3, h3.x, a2); a3 = fmaf(v3, h3.y, a3);
    a0 = fmaf(v4, l4.x, a0); a1 = fmaf(v4, l4.y, a1);
    a2 = fmaf(v4, h4.x, a2); a3 = fmaf(v4, h4.y, a3);
    a0 = fmaf(v5, l5.x, a0); a1 = fmaf(v5, l5.y, a1);
    a2 = fmaf(v5, h5.x, a2); a3 = fmaf(v5, h5.y, a3);
    a0 = fmaf(v6, l6.x, a0); a1 = fmaf(v6, l6.y, a1);
    a2 = fmaf(v6, h6.x, a2); a3 = fmaf(v6, h6.y, a3);
    a0 = fmaf(v7, l7.x, a0); a1 = fmaf(v7, l7.y, a1);
    a2 = fmaf(v7, h7.x, a2); a3 = fmaf(v7, h7.y, a3);
  }

  for (; j < end; ++j) {
    u32 pk = csr[j];
    GATHER_FMA(pk);
  }
#undef GATHER_FMA

  const float4 bv = *(const float4*)&b1[lt * 4];
  a0 = fmaxf(a0 + bv.x, 0.f);
  a1 = fmaxf(a1 + bv.y, 0.f);
  a2 = fmaxf(a2 + bv.z, 0.f);
  a3 = fmaxf(a3 + bv.w, 0.f);

  // --- fused GEMM2 epilogue: h2[row] = z1row @ W2 ---
  float* zrow = z1s[tb];
  zrow[lt * 4 + 0] = a0;
  zrow[lt * 4 + 1] = a1;
  zrow[lt * 4 + 2] = a2;
  zrow[lt * 4 + 3] = a3;
  // same wave: LDS ops in order, no barrier needed
  float o0 = 0.f, o1 = 0.f;
#pragma unroll
  for (int k = 0; k < D_HID; k += 4) {
    float4 z4 = *(const float4*)&zrow[k];
    o0 = fmaf(z4.x, w2s[(k + 0) * D_EMB + 2 * lt], o0);
    o1 = fmaf(z4.x, w2s[(k + 0) * D_EMB + 2 * lt + 1], o1);
    o0 = fmaf(z4.y, w2s[(k + 1) * D_EMB + 2 * lt], o0);
    o1 = fmaf(z4.y, w2s[(k + 1) * D_EMB + 2 * lt + 1], o1);
    o0 = fmaf(z4.z, w2s[(k + 2) * D_EMB + 2 * lt], o0);
    o1 = fmaf(z4.z, w2s[(k + 2) * D_EMB + 2 * lt + 1], o1);
    o0 = fmaf(z4.w, w2s[(k + 3) * D_EMB + 2 * lt], o0);
    o1 = fmaf(z4.w, w2s[(k + 3) * D_EMB + 2 * lt + 1], o1);
  }
  u32 o = (u32)f2bf(o0) | ((u32)f2bf(o1) << 16);
  ((u32*)h2)[((u32)row << 4) + lt] = o;   // 16 lanes x u32 = 64B row
}

// ---------------------------------------------------------------------------
// Team-vectorized CSR SPMM (layer 2, bf16 in/out): TEAM = D/4 lanes per row.
template <int D, bool RELU>
__global__ __launch_bounds__(256) void spmm_csr_kernel(
    const int* __restrict__ rs, const u32* __restrict__ csr,
    const u16* __restrict__ in, const float* __restrict__ bias,
    u16* __restrict__ out, int M) {
  constexpr int TEAM = D / 4;
  constexpr int SH = (D == 64) ? 6 : 5;   // u16 elems per row = D = 1<<SH
  const int lt = threadIdx.x % TEAM;
  const int row = blockIdx.x * (256 / TEAM) + threadIdx.x / TEAM;
  if (row >= M) return;
  const int start = (row == 0) ? 0 : rs[row - 1];
  const int end = rs[row];
  const float qs = 1.f / 32768.f;
  const u16* inp = in + lt * 4;

  float a0 = 0.f, a1 = 0.f, a2 = 0.f, a3 = 0.f;
  int j = start;

  // head peel to 16B-aligned csr index
  int head = (4 - (start & 3)) & 3;
  if (head > end - start) head = end - start;
  for (int h = 0; h < head; ++h, ++j) {
    u32 pk = csr[j];
    uint2 w = *(const uint2*)(inp + ((pk >> 15) << SH));
    float v = (float)(pk & 32767u) * qs;
    a0 = fmaf(v, bf2f(w.x), a0); a1 = fmaf(v, bf2f_hi(w.x), a1);
    a2 = fmaf(v, bf2f(w.y), a2); a3 = fmaf(v, bf2f_hi(w.y), a3);
  }

  // 8-edge main loop: 2 independent csr uint4 + 8 gathers in flight
  for (; j + 8 <= end; j += 8) {
    uint4 pa = *(const uint4*)&csr[j];
    uint4 pb = *(const uint4*)&csr[j + 4];
    uint2 w0 = *(const uint2*)(inp + ((pa.x >> 15) << SH));
    uint2 w1 = *(const uint2*)(inp + ((pa.y >> 15) << SH));
    uint2 w2 = *(const uint2*)(inp + ((pa.z >> 15) << SH));
    uint2 w3 = *(const uint2*)(inp + ((pa.w >> 15) << SH));
    uint2 w4 = *(const uint2*)(inp + ((pb.x >> 15) << SH));
    uint2 w5 = *(const uint2*)(inp + ((pb.y >> 15) << SH));
    uint2 w6 = *(const uint2*)(inp + ((pb.z >> 15) << SH));
    uint2 w7 = *(const uint2*)(inp + ((pb.w >> 15) << SH));
    float v0 = (float)(pa.x & 32767u) * qs;
    float v1 = (float)(pa.y & 32767u) * qs;
    float v2 = (float)(pa.z & 32767u) * qs;
    float v3 = (float)(pa.w & 32767u) * qs;
    float v4 = (float)(pb.x & 32767u) * qs;
    float v5 = (float)(pb.y & 32767u) * qs;
    float v6 = (float)(pb.z & 32767u) * qs;
    float v7 = (float)(pb.w & 32767u) * qs;
    a0 = fmaf(v0, bf2f(w0.x), a0); a1 = fmaf(v0, bf2f_hi(w0.x), a1);
    a2 = fmaf(v0, bf2f(w0.y), a2); a3 = fmaf(v0, bf2f_hi(w0.y), a3);
    a0 = fmaf(v1, bf2f(w1.x), a0); a1 = fmaf(v1, bf2f_hi(w1.x), a1);
    a2 = fmaf(v1, bf2f(w1.y), a2); a3 = fmaf(v1, bf2f_hi(w1.y), a3);
    a0 = fmaf(v2, bf2f(w2.x), a0); a1 = fmaf(v2, bf2f_hi(w2.x), a1);
    a2 = fmaf(v2, bf2f(w2.y), a2); a3 = fmaf(v2, bf2f_hi(w2.y), a3);
    a0 = fmaf(v3, bf2f(w3.x), a0); a1 = fmaf(v3, bf2f_hi(w3.x), a1);
    a2 = fmaf(v3, bf2f(w3.y), a2); a3 = fmaf(v3, bf2f_hi(w3.y), a3);
    a0 = fmaf(v4, bf2f(w4.x), a0); a1 = fmaf(v4, bf2f_hi(w4.x), a1);
    a2 = fmaf(v4, bf2f(w4.y), a2); a3 = fmaf(v4, bf2f_hi(w4.y), a3);
    a0 = fmaf(v5, bf2f(w5.x), a0); a1 = fmaf(v5, bf2f_hi(w5.x), a1);
    a2 = fmaf(v5, bf2f(w5.y), a2); a3 = fmaf(v5, bf2f_hi(w5.y), a3);
    a0 = fmaf(v6, bf2f(w6.x), a0); a1 = fmaf(v6, bf2f_hi(w6.x), a1);
    a2 = fmaf(v6, bf2f(w6.y), a2); a3 = fmaf(v6, bf2f_hi(w6.y), a3);
    a0 = fmaf(v7, bf2f(w7.x), a0); a1 = fmaf(v7, bf2f_hi(w7.x), a1);
    a2 = fmaf(v7, bf2f(w7.y), a2); a3 = fmaf(v7, bf2f_hi(w7.y), a3);
  }

  for (; j + 4 <= end; j += 4) {
    uint4 p = *(const uint4*)&csr[j];
    uint2 w0 = *(const uint2*)(inp + ((p.x >> 15) << SH));
    uint2 w1 = *(const uint2*)(inp + ((p.y >> 15) << SH));
    uint2 w2 = *(const uint2*)(inp + ((p.z >> 15) << SH));
    uint2 w3 = *(const uint2*)(inp + ((p.w >> 15) << SH));
    float v0 = (float)(p.x & 32767u) * qs;
    float v1 = (float)(p.y & 32767u) * qs;
    float v2 = (float)(p.z & 32767u) * qs;
    float v3 = (float)(p.w & 32767u) * qs;
    a0 = fmaf(v0, bf2f(w0.x), a0); a1 = fmaf(v0, bf2f_hi(w0.x), a1);
    a2 = fmaf(v0, bf2f(w0.y), a2); a3 = fmaf(v0, bf2f_hi(w0.y), a3);
    a0 = fmaf(v1, bf2f(w1.x), a0); a1 = fmaf(v1, bf2f_hi(w1.x), a1);
    a2 = fmaf(v1, bf2f(w1.y), a2); a3 = fmaf(v1, bf2f_hi(w1.y), a3);
    a0 = fmaf(v2, bf2f(w2.x), a0); a1 = fmaf(v2, bf2f_hi(w2.x), a1);
    a2 = fmaf(v2, bf2f(w2.y), a2); a3 = fmaf(v2, bf2f_hi(w2.y), a3);
    a0 = fmaf(v3, bf2f(w3.x), a0); a1 = fmaf(v3, bf2f_hi(w3.x), a1);
    a2 = fmaf(v3, bf2f(w3.y), a2); a3 = fmaf(v3, bf2f_hi(w3.y), a3);
  }
  for (; j < end; ++j) {
    u32 pk = csr[j];
    uint2 w = *(const uint2*)(inp + ((pk >> 15) << SH));
    float v = (float)(pk & 32767u) * qs;
    a0 = fmaf(v, bf2f(w.x), a0); a1 = fmaf(v, bf2f_hi(w.x), a1);
    a2 = fmaf(v, bf2f(w.y), a2); a3 = fmaf(v, bf2f_hi(w.y), a3);
  }
  const float4 bv = *(const float4*)&bias[lt * 4];
  a0 += bv.x; a1 += bv.y; a2 += bv.z; a3 += bv.w;
  if (RELU) {
    a0 = fmaxf(a0, 0.f); a1 = fmaxf(a1, 0.f);
    a2 = fmaxf(a2, 0.f); a3 = fmaxf(a3, 0.f);
  }
  uint2 o;
  o.x = (u32)f2bf(a0) | ((u32)f2bf(a1) << 16);
  o.y = (u32)f2bf(a2) | ((u32)f2bf(a3) << 16);
  *(uint2*)&out[((u32)row << SH) + lt * 4] = o;
}

// ---------------------------------------------------------------------------
// Decoder: scores[e] = dot(z2[src], z2[dst]). 2 edges per thread,
// all 8 uint4 gathers issued before the dot-product chains.
__global__ __launch_bounds__(256) void decode_kernel(
    const int* __restrict__ ei, const u16* __restrict__ z2,
    float* __restrict__ out, int nE) {
  const int t = blockIdx.x * 256 + threadIdx.x;
  const int e0 = t * 2;
  if (e0 >= nE) return;
  const bool two = (e0 + 1 < nE);

  const int2 ss = *(const int2*)&ei[e0];
  const int2 dd = *(const int2*)&ei[nE + e0];

  const uint4* za = (const uint4*)(z2 + ((u32)ss.x << 5));
  const uint4* zb = (const uint4*)(z2 + ((u32)dd.x << 5));
  const uint4* zc = (const uint4*)(z2 + ((u32)(two ? ss.y : ss.x) << 5));
  const uint4* zd = (const uint4*)(z2 + ((u32)(two ? dd.y : dd.x) << 5));

  uint4 A[2], B[2], C[2], Dv[2];
  A[0] = za[0]; A[1] = za[1];
  B[0] = zb[0]; B[1] = zb[1];
  C[0] = zc[0]; C[1] = zc[1];
  Dv[0] = zd[0]; Dv[1] = zd[1];
  uint4 A2[2], B2[2], C2[2], D2[2];
  A2[0] = za[2]; A2[1] = za[3];
  B2[0] = zb[2]; B2[1] = zb[3];
  C2[0] = zc[2]; C2[1] = zc[3];
  D2[0] = zd[2]; D2[1] = zd[3];

  float acc0 = 0.f, acc1 = 0.f;
  float a8[8], b8[8];
#pragma unroll
  for (int c = 0; c < 2; ++c) {
    unpack8(A[c], a8); unpack8(B[c], b8);
#pragma unroll
    for (int k = 0; k < 8; ++k) acc0 = fmaf(a8[k], b8[k], acc0);
    unpack8(A2[c], a8); unpack8(B2[c], b8);
#pragma unroll
    for (int k = 0; k < 8; ++k) acc0 = fmaf(a8[k], b8[k], acc0);
    unpack8(C[c], a8); unpack8(Dv[c], b8);
#pragma unroll
    for (int k = 0; k < 8; ++k) acc1 = fmaf(a8[k], b8[k], acc1);
    unpack8(C2[c], a8); unpack8(D2[c], b8);
#pragma unroll
    for (int k = 0; k < 8; ++k) acc1 = fmaf(a8[k], b8[k], acc1);
  }
  out[e0] = acc0;
  if (two) out[e0 + 1] = acc1;
}

// ---------------------------------------------------------------------------
extern "C" void kernel_launch(void* const* d_in, const int* in_sizes, int n_in,
                              void* d_out, int out_size, void* d_ws, size_t ws_size,
                              hipStream_t stream) {
  const float* x       = (const float*)d_in[0];
  const int*   adj_src = (const int*)d_in[1];
  const int*   adj_dst = (const int*)d_in[2];
  const float* adj_val = (const float*)d_in[3];
  const int*   ei      = (const int*)d_in[4];
  const float* W1      = (const float*)d_in[5];
  const float* b1      = (const float*)d_in[6];
  const float* W2      = (const float*)d_in[7];
  const float* b2      = (const float*)d_in[8];

  const int M   = in_sizes[0] / D_IN;      // 100000
  const int nnz = in_sizes[1];             // 3200000
  const int nE  = in_sizes[4] / 2;         // 2000000

  const int NBUK = (M + BROWS - 1) / BROWS;  // 391

  // Workspace (76.8 MB):
  //   [0, 12.8):       csr packed u32
  //   [12.8, 38.4):    payload int2 (dead after sort) -> h1 fp8 [12.8,19.2),
  //                    h2 bf16 [19.2, 25.6)
  //   [38.4, 44.8):    z2 bf16 [M,32]
  //   [60.0, +32KB):   gswz (pre-swizzled W1 bf16 fragments)
  char* ws = (char*)d_ws;
  u32*   csr     = (u32*)(ws);
  int2*  payload = (int2*)(ws + (size_t)nnz * 4);
  u8*    h1      = (u8*)(ws + (size_t)nnz * 4);
  u16*   h2      = (u16*)(ws + (size_t)nnz * 4 + (size_t)M * D_HID);
  u16*   z2      = (u16*)(ws + (size_t)nnz * 12);
  uint4* gswz    = (uint4*)(ws + 60ull * 1024 * 1024);

  // Small scratch in d_out (8 MB, dead until decode):
  int* rs    = (int*)d_out;                 // M ints
  int* bscan = (int*)d_out + 112 * 1024;    // NBUK+1 ints
  int* cur   = (int*)d_out + 120 * 1024;    // NBUK ints

  // --- W1 swizzle ---
  w1_swizzle_kernel<<<8, 256, 0, stream>>>(W1, gswz);

  // --- bucket partition ---
  hipMemsetAsync(bscan, 0, (size_t)(NBUK + 1) * 4, stream);
  bin_count<<<256, 256, 0, stream>>>(adj_dst, bscan, nnz, NBUK);
  bin_scan<<<1, 256, 0, stream>>>(bscan, cur, NBUK);
  partition_kernel<<<(nnz + TILE - 1) / TILE, PBS, 0, stream>>>(
      adj_src, adj_dst, adj_val, cur, payload, nnz, NBUK);

  // --- bucket-local counting sort (dstlow x src-quartile bins) ---
  bucket_sort_kernel<<<NBUK, SBS, 0, stream>>>(bscan, payload, csr, rs, M);

  // --- GEMM1 via MFMA (fp8 h1 output) ---
  gemm1_mfma_kernel<<<(M + 63) / 64, 256, 0, stream>>>(x, gswz, h1, M);

  // --- SPMM1 + b1 + ReLU + GEMM2 fused (16-lane teams, fp8 gathers) ---
  spmm1_gemm2_fused<<<(M + 15) / 16, 256, 0, stream>>>(
      rs, csr, h1, b1, W2, h2, M);

  // --- SPMM2 + b2 (8-lane teams, bf16) ---
  spmm_csr_kernel<D_EMB, false><<<(M + 31) / 32, 256, 0, stream>>>(
      rs, csr, h2, b2, z2, M);

  // --- Decode (2 edges/thread, overwrites d_out scratch) ---
  decode_kernel<<<(nE / 2 + 255) / 256, 256, 0, stream>>>(ei, z2, (float*)d_out, nE);
}